// Round 1
// baseline (105.607 us; speedup 1.0000x reference)
//
#include <hip/hip_runtime.h>
#include <hip/hip_bf16.h>
#include <string.h>

// FullAttention forward: B=2, L=S=2048, H=16, E=D=64, fp32 in/out.
// Flash-attention, fp16 MFMA (16x16x32), swapped QK^T (S^T = K*Q^T) so the
// softmax reduce is lane-local + 2 shfl_xor. V staged transposed in LDS.
// All LDS tiles XOR-swizzled (byte ^= (row&7)<<4) to kill 16-way conflicts.

#define NB 2
#define LL 2048
#define SS 2048
#define HH 16
#define EE 64
#define DD 64
#define KVB 64
#define NT (SS / KVB) /* 32 */

typedef _Float16 f16x8 __attribute__((ext_vector_type(8)));
typedef float f32x4 __attribute__((ext_vector_type(4)));
typedef unsigned uint2v __attribute__((ext_vector_type(2)));

// pack two f32 -> two f16 (RTZ) in one u32 (single v_cvt_pkrtz_f16_f32)
__device__ __forceinline__ unsigned pk2h(float a, float b) {
    auto h = __builtin_amdgcn_cvt_pkrtz(a, b);
    unsigned u;
    __builtin_memcpy(&u, &h, 4);
    return u;
}

__global__ __launch_bounds__(256) void fattn(const float* __restrict__ Q,
                                             const float* __restrict__ K,
                                             const float* __restrict__ V,
                                             float* __restrict__ O) {
    // K tile: [s=64][e=64] f16 (swizzled). V^T tile: [d=64][s=64] f16 (swizzled).
    // P: per-wave [q=16][s=64] f16 (swizzled).
    __shared__ __align__(16) short Klds[KVB * 64];
    __shared__ __align__(16) short Vtlds[64 * KVB];
    __shared__ __align__(16) short Plds[4][16 * 64];

    const int tid  = threadIdx.x;
    const int lane = tid & 63;
    const int wid  = tid >> 6;       // 0..3
    const int g    = (lane >> 4) & 3;
    const int c    = lane & 15;

    const int bid = blockIdx.x;
    const int bh  = bid >> 5;        // 0..31  (consecutive blocks share K/V)
    const int qt  = bid & 31;
    const int b   = bh >> 4;
    const int h   = bh & 15;
    const int q0  = qt * 64;

    // ---- Q fragments (B-operand of swapped QK^T): q = lane&15, e = g*8+j ----
    const int qrow = q0 + wid * 16 + c;
    const float* qptr = Q + (((size_t)b * LL + qrow) * HH + h) * EE;
    const float qs = 0.125f * 1.44269504088896340736f; // scale * log2(e)
    f16x8 qf[2];
#pragma unroll
    for (int kk = 0; kk < 2; ++kk) {
        f32x4 a0 = *(const f32x4*)(qptr + kk * 32 + g * 8);
        f32x4 a1 = *(const f32x4*)(qptr + kk * 32 + g * 8 + 4);
        union { f16x8 v; unsigned u[4]; } cv;
        cv.u[0] = pk2h(a0[0] * qs, a0[1] * qs);
        cv.u[1] = pk2h(a0[2] * qs, a0[3] * qs);
        cv.u[2] = pk2h(a1[0] * qs, a1[1] * qs);
        cv.u[3] = pk2h(a1[2] * qs, a1[3] * qs);
        qf[kk] = cv.v;
    }

    f32x4 osacc[4]; // O^T acc: frag fr -> rows d=16*fr+4g+r, col q=c
    const f32x4 fzero = {0.f, 0.f, 0.f, 0.f};
#pragma unroll
    for (int i = 0; i < 4; ++i) osacc[i] = fzero;
    float m_run = -1e30f;
    float l_run = 0.f;

    const int km = tid & 15;  // staging col group
    const int kr = tid >> 4;  // staging row group 0..15

    for (int it = 0; it < NT; ++it) {
        const int s_glob = it * KVB;

        // ---- issue global loads for this tile (latency overlaps barrier) ----
        f32x4 kreg[4];
#pragma unroll
        for (int p = 0; p < 4; ++p) {
            int s = kr + p * 16;
            kreg[p] = *(const f32x4*)(K + (((size_t)b * SS + s_glob + s) * HH + h) * EE + km * 4);
        }
        f32x4 vreg[4];
#pragma unroll
        for (int p = 0; p < 4; ++p) {
            int s = kr * 4 + p;
            vreg[p] = *(const f32x4*)(V + (((size_t)b * SS + s_glob + s) * HH + h) * DD + km * 4);
        }

        __syncthreads(); // previous tile's LDS reads complete

        // ---- stage K tile (row-major, swizzled) ----
#pragma unroll
        for (int p = 0; p < 4; ++p) {
            int s = kr + p * 16;
            uint2v w;
            w.x = pk2h(kreg[p][0], kreg[p][1]);
            w.y = pk2h(kreg[p][2], kreg[p][3]);
            int byte = (s * 128 + km * 8) ^ ((s & 7) << 4);
            *(uint2v*)((char*)Klds + byte) = w;
        }
        // ---- stage V^T tile (4x4 register transpose, swizzled) ----
#pragma unroll
        for (int i = 0; i < 4; ++i) {
            int d = km * 4 + i;
            uint2v w;
            w.x = pk2h(vreg[0][i], vreg[1][i]);
            w.y = pk2h(vreg[2][i], vreg[3][i]);
            int byte = (d * 128 + kr * 8) ^ ((d & 7) << 4);
            *(uint2v*)((char*)Vtlds + byte) = w;
        }

        __syncthreads(); // tile staged

        // ---- QK^T: S^T[s][q] frags, A = K (s x e), B = Q^T (e x q) ----
        f32x4 st[4];
#pragma unroll
        for (int fr = 0; fr < 4; ++fr) st[fr] = fzero;
#pragma unroll
        for (int fr = 0; fr < 4; ++fr) {
            int s = fr * 16 + c;
            f16x8 kf0 = *(const f16x8*)((const char*)Klds + ((s * 128 + 16 * g) ^ ((s & 7) << 4)));
            st[fr] = __builtin_amdgcn_mfma_f32_16x16x32_f16(kf0, qf[0], st[fr], 0, 0, 0);
            f16x8 kf1 = *(const f16x8*)((const char*)Klds + ((s * 128 + 64 + 16 * g) ^ ((s & 7) << 4)));
            st[fr] = __builtin_amdgcn_mfma_f32_16x16x32_f16(kf1, qf[1], st[fr], 0, 0, 0);
        }

        // ---- online softmax in log2 domain (per lane: q = c, 16 s-values) ----
        float pmax = st[0][0];
#pragma unroll
        for (int fr = 0; fr < 4; ++fr)
#pragma unroll
            for (int r = 0; r < 4; ++r) pmax = fmaxf(pmax, st[fr][r]);
        pmax = fmaxf(pmax, __shfl_xor(pmax, 16));
        pmax = fmaxf(pmax, __shfl_xor(pmax, 32));
        float mnew  = fmaxf(m_run, pmax);
        float alpha = exp2f(m_run - mnew);
        float tsum = 0.f;
#pragma unroll
        for (int fr = 0; fr < 4; ++fr)
#pragma unroll
            for (int r = 0; r < 4; ++r) {
                float e = exp2f(st[fr][r] - mnew);
                st[fr][r] = e;
                tsum += e;
            }
        tsum += __shfl_xor(tsum, 16);
        tsum += __shfl_xor(tsum, 32);
        l_run = l_run * alpha + tsum;
        m_run = mnew;
#pragma unroll
        for (int fr = 0; fr < 4; ++fr)
#pragma unroll
            for (int r = 0; r < 4; ++r) osacc[fr][r] *= alpha;

        // ---- P -> per-wave LDS ([q][s] f16, swizzled), read back as B-frags ----
        short* plb = &Plds[wid][0];
#pragma unroll
        for (int fr = 0; fr < 4; ++fr) {
            uint2v w;
            w.x = pk2h(st[fr][0], st[fr][1]);
            w.y = pk2h(st[fr][2], st[fr][3]);
            int byte = (c * 128 + fr * 32 + g * 8) ^ ((c & 7) << 4);
            *(uint2v*)((char*)plb + byte) = w;
        }
        f16x8 pb0 = *(const f16x8*)((const char*)plb + ((c * 128 + 16 * g) ^ ((c & 7) << 4)));
        f16x8 pb1 = *(const f16x8*)((const char*)plb + ((c * 128 + 64 + 16 * g) ^ ((c & 7) << 4)));

        // ---- PV: O^T += V^T (d x s) * P^T (s x q) ----
#pragma unroll
        for (int fr = 0; fr < 4; ++fr) {
            int d = fr * 16 + c;
            f16x8 vf0 = *(const f16x8*)((const char*)Vtlds + ((d * 128 + 16 * g) ^ ((d & 7) << 4)));
            osacc[fr] = __builtin_amdgcn_mfma_f32_16x16x32_f16(vf0, pb0, osacc[fr], 0, 0, 0);
            f16x8 vf1 = *(const f16x8*)((const char*)Vtlds + ((d * 128 + 64 + 16 * g) ^ ((d & 7) << 4)));
            osacc[fr] = __builtin_amdgcn_mfma_f32_16x16x32_f16(vf1, pb1, osacc[fr], 0, 0, 0);
        }
    }

    // ---- epilogue: O[q][d] = O^T / l ----
    float invl = 1.f / l_run;
    float* optr = O + (((size_t)b * LL + qrow) * HH + h) * DD;
#pragma unroll
    for (int fr = 0; fr < 4; ++fr) {
        f32x4 o;
        o[0] = osacc[fr][0] * invl;
        o[1] = osacc[fr][1] * invl;
        o[2] = osacc[fr][2] * invl;
        o[3] = osacc[fr][3] * invl;
        *(f32x4*)(optr + fr * 16 + g * 4) = o;
    }
}

extern "C" void kernel_launch(void* const* d_in, const int* in_sizes, int n_in,
                              void* d_out, int out_size, void* d_ws, size_t ws_size,
                              hipStream_t stream) {
    const float* Q = (const float*)d_in[0];
    const float* K = (const float*)d_in[1];
    const float* V = (const float*)d_in[2];
    float* Op = (float*)d_out;
    dim3 grid(NB * HH * (LL / 64)); // 1024 blocks: bh-major, 32 q-tiles each
    dim3 block(256);
    hipLaunchKernelGGL(fattn, grid, block, 0, stream, Q, K, V, Op);
}

// Round 2
// 90.305 us; speedup vs baseline: 1.1694x; 1.1694x over previous
//
#include <hip/hip_runtime.h>
#include <hip/hip_bf16.h>
#include <string.h>

// FullAttention fwd: B=2, L=S=2048, H=16, E=D=64, fp32 in/out.
// R2: prep pass converts K -> f16 and V -> V^T f16 into d_ws, laid out as the
// pre-swizzled LDS tile image. Attention kernel stages tiles with
// global_load_lds (DMA, double-buffered, 2-phase pipeline), QBLK=128 per
// block (4 waves x 32 q-rows), fp16 MFMA 16x16x32, swapped QK^T, defer-max.

#define NB 2
#define LL 2048
#define SS 2048
#define HH 16
#define EE 64
#define DD 64
#define KVB 64
#define NT (SS / KVB) /* 32 */
#define QBLK 128
#define NWG (NB * HH * (LL / QBLK)) /* 512 */

typedef _Float16 f16x8 __attribute__((ext_vector_type(8)));
typedef float f32x4 __attribute__((ext_vector_type(4)));
typedef unsigned uint2v __attribute__((ext_vector_type(2)));
typedef unsigned uint4v __attribute__((ext_vector_type(4)));
typedef const __attribute__((address_space(1))) void* gas_p;
typedef __attribute__((address_space(3))) void* las_p;

__device__ __forceinline__ unsigned pk2h(float a, float b) {
    auto h = __builtin_amdgcn_cvt_pkrtz(a, b);
    unsigned u;
    __builtin_memcpy(&u, &h, 4);
    return u;
}

__device__ __forceinline__ void gll16(const void* g, void* l) {
    __builtin_amdgcn_global_load_lds((gas_p)g, (las_p)l, 16, 0, 0);
}

// ---------------- prep: K -> f16 swizzled tile image ----------------
// Kh tile (8KB) layout: byte a = (s*128 + e*2) ^ ((s&7)<<4) holds f16 K[s0+s][e]
__global__ __launch_bounds__(256) void prepK(const float* __restrict__ K,
                                             unsigned short* __restrict__ Kh) {
    const int tile = blockIdx.x;      // bh*NT + it
    const int it = tile & (NT - 1);
    const int bh = tile >> 5;
    const int b = bh >> 4, h = bh & 15;
    const int t = threadIdx.x;
    const int s = t >> 2, ec = t & 3;
    const float* src = K + (((size_t)b * SS + it * KVB + s) * HH + h) * EE + ec * 16;
    f32x4 x0 = ((const f32x4*)src)[0];
    f32x4 x1 = ((const f32x4*)src)[1];
    f32x4 x2 = ((const f32x4*)src)[2];
    f32x4 x3 = ((const f32x4*)src)[3];
    uint4v c0, c1;
    c0.x = pk2h(x0[0], x0[1]); c0.y = pk2h(x0[2], x0[3]);
    c0.z = pk2h(x1[0], x1[1]); c0.w = pk2h(x1[2], x1[3]);
    c1.x = pk2h(x2[0], x2[1]); c1.y = pk2h(x2[2], x2[3]);
    c1.z = pk2h(x3[0], x3[1]); c1.w = pk2h(x3[2], x3[3]);
    char* dst = (char*)Kh + (size_t)tile * 8192;
    const int sw = (s & 7) << 4;
    *(uint4v*)(dst + ((s * 128 + ec * 32) ^ sw)) = c0;
    *(uint4v*)(dst + ((s * 128 + ec * 32 + 16) ^ sw)) = c1;
}

// ---------------- prep: V -> V^T f16 swizzled tile image ----------------
// Vth tile (8KB) layout: byte a = (d*128 + s*2) ^ ((d&7)<<4) holds f16 V[s0+s][d]
__global__ __launch_bounds__(256) void prepV(const float* __restrict__ V,
                                             unsigned short* __restrict__ Vth) {
    __shared__ float Vt[64 * 68];
    const int tile = blockIdx.x;
    const int it = tile & (NT - 1);
    const int bh = tile >> 5;
    const int b = bh >> 4, h = bh & 15;
    const int t = threadIdx.x;
    {
        const int s = t >> 2, dc = t & 3;
        const float* src = V + (((size_t)b * SS + it * KVB + s) * HH + h) * DD + dc * 16;
        f32x4 x0 = ((const f32x4*)src)[0];
        f32x4 x1 = ((const f32x4*)src)[1];
        f32x4 x2 = ((const f32x4*)src)[2];
        f32x4 x3 = ((const f32x4*)src)[3];
        float* row = Vt + s * 68 + dc * 16;
        ((f32x4*)row)[0] = x0; ((f32x4*)row)[1] = x1;
        ((f32x4*)row)[2] = x2; ((f32x4*)row)[3] = x3;
    }
    __syncthreads();
    {
        const int d = t >> 2, sc = t & 3;
        float w[16];
#pragma unroll
        for (int j = 0; j < 16; ++j) w[j] = Vt[(sc * 16 + j) * 68 + d];
        uint4v c0, c1;
        c0.x = pk2h(w[0], w[1]); c0.y = pk2h(w[2], w[3]);
        c0.z = pk2h(w[4], w[5]); c0.w = pk2h(w[6], w[7]);
        c1.x = pk2h(w[8], w[9]); c1.y = pk2h(w[10], w[11]);
        c1.z = pk2h(w[12], w[13]); c1.w = pk2h(w[14], w[15]);
        char* dst = (char*)Vth + (size_t)tile * 8192;
        const int sw = (d & 7) << 4;
        *(uint4v*)(dst + ((d * 128 + sc * 32) ^ sw)) = c0;
        *(uint4v*)(dst + ((d * 128 + sc * 32 + 16) ^ sw)) = c1;
    }
}

// ---------------- main attention kernel ----------------
__global__ __launch_bounds__(256) void fattn2(const unsigned short* __restrict__ Kh,
                                              const unsigned short* __restrict__ Vth,
                                              const float* __restrict__ Q,
                                              float* __restrict__ O) {
    __shared__ __align__(16) char K0s[8192], K1s[8192], V0s[8192], V1s[8192];
    __shared__ __align__(16) char Pl[4][4096];

    const int tid = threadIdx.x;
    const int lane = tid & 63;
    const int wid = tid >> 6;      // 0..3
    const int g = lane >> 4;       // 0..3
    const int c = lane & 15;

    // bijective XCD swizzle: 512 wgs, 8 XCDs -> each XCD gets 64 contiguous
    const int bid0 = blockIdx.x;
    const int bid = (bid0 & 7) * (NWG >> 3) + (bid0 >> 3);
    const int bh = bid >> 4;       // 0..31
    const int qt = bid & 15;
    const int b = bh >> 4, h = bh & 15;
    const int q0 = qt * QBLK + wid * 32;

    // ---- Q fragments: qf[qq][half], B-operand (n=q=c, k=e=half*32+g*8+j) ----
    const float qs = 0.125f * 1.44269504088896340736f; // scale * log2(e)
    f16x8 qf[2][2];
#pragma unroll
    for (int qq = 0; qq < 2; ++qq) {
        const int qrow = q0 + qq * 16 + c;
        const float* qptr = Q + (((size_t)b * LL + qrow) * HH + h) * EE;
#pragma unroll
        for (int kk = 0; kk < 2; ++kk) {
            f32x4 a0 = *(const f32x4*)(qptr + kk * 32 + g * 8);
            f32x4 a1 = *(const f32x4*)(qptr + kk * 32 + g * 8 + 4);
            union { f16x8 v; unsigned u[4]; } cv;
            cv.u[0] = pk2h(a0[0] * qs, a0[1] * qs);
            cv.u[1] = pk2h(a0[2] * qs, a0[3] * qs);
            cv.u[2] = pk2h(a1[0] * qs, a1[1] * qs);
            cv.u[3] = pk2h(a1[2] * qs, a1[3] * qs);
            qf[qq][kk] = cv.v;
        }
    }

    f32x4 osacc[4][2];
    const f32x4 fzero = {0.f, 0.f, 0.f, 0.f};
#pragma unroll
    for (int fr = 0; fr < 4; ++fr) { osacc[fr][0] = fzero; osacc[fr][1] = fzero; }
    float m0 = -1e30f, m1 = -1e30f, l0 = 0.f, l1 = 0.f;

    const char* Kg = (const char*)Kh + (size_t)bh * (NT * 8192);
    const char* Vg = (const char*)Vth + (size_t)bh * (NT * 8192);

    auto STAGE = [&](int it, char* Ks, char* Vs) {
        const size_t off = (size_t)it * 8192 + wid * 2048 + lane * 16;
        gll16(Kg + off, Ks + wid * 2048);
        gll16(Kg + off + 1024, Ks + wid * 2048 + 1024);
        gll16(Vg + off, Vs + wid * 2048);
        gll16(Vg + off + 1024, Vs + wid * 2048 + 1024);
    };

    auto COMPUTE = [&](const char* Ks, const char* Vs) {
        // ---- QK^T: st[fr][qq], S^T rows s = fr*16+4g+r, col q = qq*16+c ----
        f32x4 st[4][2];
#pragma unroll
        for (int fr = 0; fr < 4; ++fr) { st[fr][0] = fzero; st[fr][1] = fzero; }
        __builtin_amdgcn_s_setprio(1);
#pragma unroll
        for (int fr = 0; fr < 4; ++fr) {
            const int s = fr * 16 + c;
            const int sw = (s & 7) << 4;
            f16x8 k0 = *(const f16x8*)(Ks + ((s * 128 + g * 16) ^ sw));
            f16x8 k1 = *(const f16x8*)(Ks + ((s * 128 + 64 + g * 16) ^ sw));
            st[fr][0] = __builtin_amdgcn_mfma_f32_16x16x32_f16(k0, qf[0][0], st[fr][0], 0, 0, 0);
            st[fr][0] = __builtin_amdgcn_mfma_f32_16x16x32_f16(k1, qf[0][1], st[fr][0], 0, 0, 0);
            st[fr][1] = __builtin_amdgcn_mfma_f32_16x16x32_f16(k0, qf[1][0], st[fr][1], 0, 0, 0);
            st[fr][1] = __builtin_amdgcn_mfma_f32_16x16x32_f16(k1, qf[1][1], st[fr][1], 0, 0, 0);
        }
        __builtin_amdgcn_s_setprio(0);

        // ---- online softmax (log2 domain), defer-max (THR=8) ----
        float pmax0 = st[0][0][0], pmax1 = st[0][1][0];
#pragma unroll
        for (int fr = 0; fr < 4; ++fr)
#pragma unroll
            for (int r = 0; r < 4; ++r) {
                pmax0 = fmaxf(pmax0, st[fr][0][r]);
                pmax1 = fmaxf(pmax1, st[fr][1][r]);
            }
        pmax0 = fmaxf(pmax0, __shfl_xor(pmax0, 16));
        pmax0 = fmaxf(pmax0, __shfl_xor(pmax0, 32));
        pmax1 = fmaxf(pmax1, __shfl_xor(pmax1, 16));
        pmax1 = fmaxf(pmax1, __shfl_xor(pmax1, 32));
        const float dmax = fmaxf(pmax0 - m0, pmax1 - m1);
        if (!__all(dmax <= 8.0f)) {
            const float mn0 = fmaxf(m0, pmax0), mn1 = fmaxf(m1, pmax1);
            const float a0 = exp2f(m0 - mn0), a1 = exp2f(m1 - mn1);
            l0 *= a0; l1 *= a1; m0 = mn0; m1 = mn1;
#pragma unroll
            for (int fr = 0; fr < 4; ++fr)
#pragma unroll
                for (int r = 0; r < 4; ++r) {
                    osacc[fr][0][r] *= a0;
                    osacc[fr][1][r] *= a1;
                }
        }
        float ts0 = 0.f, ts1 = 0.f;
#pragma unroll
        for (int fr = 0; fr < 4; ++fr)
#pragma unroll
            for (int r = 0; r < 4; ++r) {
                float e0 = exp2f(st[fr][0][r] - m0);
                float e1 = exp2f(st[fr][1][r] - m1);
                st[fr][0][r] = e0; st[fr][1][r] = e1;
                ts0 += e0; ts1 += e1;
            }
        ts0 += __shfl_xor(ts0, 16); ts0 += __shfl_xor(ts0, 32);
        ts1 += __shfl_xor(ts1, 16); ts1 += __shfl_xor(ts1, 32);
        l0 += ts0; l1 += ts1;

        // ---- P^T -> per-wave LDS ([qloc=32][s=64] f16, swizzled) ----
        char* pw = Pl[wid];
#pragma unroll
        for (int qq = 0; qq < 2; ++qq) {
            const int qloc = qq * 16 + c;
            const int sw = (c & 7) << 4;
#pragma unroll
            for (int fr = 0; fr < 4; ++fr) {
                uint2v w;
                w.x = pk2h(st[fr][qq][0], st[fr][qq][1]);
                w.y = pk2h(st[fr][qq][2], st[fr][qq][3]);
                *(uint2v*)(pw + ((qloc * 128 + fr * 32 + g * 8) ^ sw)) = w;
            }
        }
        f16x8 pb[2][2];
#pragma unroll
        for (int qq = 0; qq < 2; ++qq) {
            const int qloc = qq * 16 + c;
            const int sw = (c & 7) << 4;
            pb[qq][0] = *(const f16x8*)(pw + ((qloc * 128 + g * 16) ^ sw));
            pb[qq][1] = *(const f16x8*)(pw + ((qloc * 128 + 64 + g * 16) ^ sw));
        }

        // ---- PV: O^T += V^T * P^T ----
        __builtin_amdgcn_s_setprio(1);
#pragma unroll
        for (int fr = 0; fr < 4; ++fr) {
            const int d = fr * 16 + c;
            const int sw = (d & 7) << 4;
            f16x8 v0 = *(const f16x8*)(Vs + ((d * 128 + g * 16) ^ sw));
            f16x8 v1 = *(const f16x8*)(Vs + ((d * 128 + 64 + g * 16) ^ sw));
            osacc[fr][0] = __builtin_amdgcn_mfma_f32_16x16x32_f16(v0, pb[0][0], osacc[fr][0], 0, 0, 0);
            osacc[fr][0] = __builtin_amdgcn_mfma_f32_16x16x32_f16(v1, pb[0][1], osacc[fr][0], 0, 0, 0);
            osacc[fr][1] = __builtin_amdgcn_mfma_f32_16x16x32_f16(v0, pb[1][0], osacc[fr][1], 0, 0, 0);
            osacc[fr][1] = __builtin_amdgcn_mfma_f32_16x16x32_f16(v1, pb[1][1], osacc[fr][1], 0, 0, 0);
        }
        __builtin_amdgcn_s_setprio(0);
    };

    STAGE(0, K0s, V0s);
    __syncthreads();
    for (int it = 0; it < NT; it += 2) {
        if (it + 1 < NT) STAGE(it + 1, K1s, V1s);
        COMPUTE(K0s, V0s);
        __syncthreads();
        if (it + 2 < NT) STAGE(it + 2, K0s, V0s);
        COMPUTE(K1s, V1s);
        __syncthreads();
    }

    // ---- epilogue ----
#pragma unroll
    for (int qq = 0; qq < 2; ++qq) {
        const float invl = 1.f / (qq ? l1 : l0);
        const int qrow = q0 + qq * 16 + c;
        float* optr = O + (((size_t)b * LL + qrow) * HH + h) * DD;
#pragma unroll
        for (int fr = 0; fr < 4; ++fr) {
            f32x4 o;
            o[0] = osacc[fr][qq][0] * invl;
            o[1] = osacc[fr][qq][1] * invl;
            o[2] = osacc[fr][qq][2] * invl;
            o[3] = osacc[fr][qq][3] * invl;
            *(f32x4*)(optr + fr * 16 + g * 4) = o;
        }
    }
}

// ---------------- fallback (R1 kernel, used if ws too small) ----------------
__global__ __launch_bounds__(256) void fattn1(const float* __restrict__ Q,
                                              const float* __restrict__ K,
                                              const float* __restrict__ V,
                                              float* __restrict__ O) {
    __shared__ __align__(16) short Klds[KVB * 64];
    __shared__ __align__(16) short Vtlds[64 * KVB];
    __shared__ __align__(16) short Plds[4][16 * 64];

    const int tid = threadIdx.x;
    const int lane = tid & 63;
    const int wid = tid >> 6;
    const int g = (lane >> 4) & 3;
    const int c = lane & 15;

    const int bid = blockIdx.x;
    const int bh = bid >> 5;
    const int qt = bid & 31;
    const int b = bh >> 4;
    const int h = bh & 15;
    const int q0 = qt * 64;

    const int qrow = q0 + wid * 16 + c;
    const float* qptr = Q + (((size_t)b * LL + qrow) * HH + h) * EE;
    const float qs = 0.125f * 1.44269504088896340736f;
    f16x8 qf[2];
#pragma unroll
    for (int kk = 0; kk < 2; ++kk) {
        f32x4 a0 = *(const f32x4*)(qptr + kk * 32 + g * 8);
        f32x4 a1 = *(const f32x4*)(qptr + kk * 32 + g * 8 + 4);
        union { f16x8 v; unsigned u[4]; } cv;
        cv.u[0] = pk2h(a0[0] * qs, a0[1] * qs);
        cv.u[1] = pk2h(a0[2] * qs, a0[3] * qs);
        cv.u[2] = pk2h(a1[0] * qs, a1[1] * qs);
        cv.u[3] = pk2h(a1[2] * qs, a1[3] * qs);
        qf[kk] = cv.v;
    }

    f32x4 osacc[4];
    const f32x4 fzero = {0.f, 0.f, 0.f, 0.f};
#pragma unroll
    for (int i = 0; i < 4; ++i) osacc[i] = fzero;
    float m_run = -1e30f;
    float l_run = 0.f;

    const int km = tid & 15;
    const int kr = tid >> 4;

    for (int it = 0; it < NT; ++it) {
        const int s_glob = it * KVB;
        f32x4 kreg[4];
#pragma unroll
        for (int p = 0; p < 4; ++p) {
            int s = kr + p * 16;
            kreg[p] = *(const f32x4*)(K + (((size_t)b * SS + s_glob + s) * HH + h) * EE + km * 4);
        }
        f32x4 vreg[4];
#pragma unroll
        for (int p = 0; p < 4; ++p) {
            int s = kr * 4 + p;
            vreg[p] = *(const f32x4*)(V + (((size_t)b * SS + s_glob + s) * HH + h) * DD + km * 4);
        }
        __syncthreads();
#pragma unroll
        for (int p = 0; p < 4; ++p) {
            int s = kr + p * 16;
            uint2v w;
            w.x = pk2h(kreg[p][0], kreg[p][1]);
            w.y = pk2h(kreg[p][2], kreg[p][3]);
            int byte = (s * 128 + km * 8) ^ ((s & 7) << 4);
            *(uint2v*)((char*)Klds + byte) = w;
        }
#pragma unroll
        for (int i = 0; i < 4; ++i) {
            int d = km * 4 + i;
            uint2v w;
            w.x = pk2h(vreg[0][i], vreg[1][i]);
            w.y = pk2h(vreg[2][i], vreg[3][i]);
            int byte = (d * 128 + kr * 8) ^ ((d & 7) << 4);
            *(uint2v*)((char*)Vtlds + byte) = w;
        }
        __syncthreads();

        f32x4 stv[4];
#pragma unroll
        for (int fr = 0; fr < 4; ++fr) stv[fr] = fzero;
#pragma unroll
        for (int fr = 0; fr < 4; ++fr) {
            int s = fr * 16 + c;
            f16x8 kf0 = *(const f16x8*)((const char*)Klds + ((s * 128 + 16 * g) ^ ((s & 7) << 4)));
            stv[fr] = __builtin_amdgcn_mfma_f32_16x16x32_f16(kf0, qf[0], stv[fr], 0, 0, 0);
            f16x8 kf1 = *(const f16x8*)((const char*)Klds + ((s * 128 + 64 + 16 * g) ^ ((s & 7) << 4)));
            stv[fr] = __builtin_amdgcn_mfma_f32_16x16x32_f16(kf1, qf[1], stv[fr], 0, 0, 0);
        }

        float pmax = stv[0][0];
#pragma unroll
        for (int fr = 0; fr < 4; ++fr)
#pragma unroll
            for (int r = 0; r < 4; ++r) pmax = fmaxf(pmax, stv[fr][r]);
        pmax = fmaxf(pmax, __shfl_xor(pmax, 16));
        pmax = fmaxf(pmax, __shfl_xor(pmax, 32));
        float mnew = fmaxf(m_run, pmax);
        float alpha = exp2f(m_run - mnew);
        float tsum = 0.f;
#pragma unroll
        for (int fr = 0; fr < 4; ++fr)
#pragma unroll
            for (int r = 0; r < 4; ++r) {
                float e = exp2f(stv[fr][r] - mnew);
                stv[fr][r] = e;
                tsum += e;
            }
        tsum += __shfl_xor(tsum, 16);
        tsum += __shfl_xor(tsum, 32);
        l_run = l_run * alpha + tsum;
        m_run = mnew;
#pragma unroll
        for (int fr = 0; fr < 4; ++fr)
#pragma unroll
            for (int r = 0; r < 4; ++r) osacc[fr][r] *= alpha;

        short* plb = &Plds[wid][0];
#pragma unroll
        for (int fr = 0; fr < 4; ++fr) {
            uint2v w;
            w.x = pk2h(stv[fr][0], stv[fr][1]);
            w.y = pk2h(stv[fr][2], stv[fr][3]);
            int byte = (c * 128 + fr * 32 + g * 8) ^ ((c & 7) << 4);
            *(uint2v*)((char*)plb + byte) = w;
        }
        f16x8 pb0 = *(const f16x8*)((const char*)plb + ((c * 128 + 16 * g) ^ ((c & 7) << 4)));
        f16x8 pb1 = *(const f16x8*)((const char*)plb + ((c * 128 + 64 + 16 * g) ^ ((c & 7) << 4)));

#pragma unroll
        for (int fr = 0; fr < 4; ++fr) {
            int d = fr * 16 + c;
            f16x8 vf0 = *(const f16x8*)((const char*)Vtlds + ((d * 128 + 16 * g) ^ ((d & 7) << 4)));
            osacc[fr] = __builtin_amdgcn_mfma_f32_16x16x32_f16(vf0, pb0, osacc[fr], 0, 0, 0);
            f16x8 vf1 = *(const f16x8*)((const char*)Vtlds + ((d * 128 + 64 + 16 * g) ^ ((d & 7) << 4)));
            osacc[fr] = __builtin_amdgcn_mfma_f32_16x16x32_f16(vf1, pb1, osacc[fr], 0, 0, 0);
        }
    }

    float invl = 1.f / l_run;
    float* optr = O + (((size_t)b * LL + qrow) * HH + h) * DD;
#pragma unroll
    for (int fr = 0; fr < 4; ++fr) {
        f32x4 o;
        o[0] = osacc[fr][0] * invl;
        o[1] = osacc[fr][1] * invl;
        o[2] = osacc[fr][2] * invl;
        o[3] = osacc[fr][3] * invl;
        *(f32x4*)(optr + fr * 16 + g * 4) = o;
    }
}

extern "C" void kernel_launch(void* const* d_in, const int* in_sizes, int n_in,
                              void* d_out, int out_size, void* d_ws, size_t ws_size,
                              hipStream_t stream) {
    const float* Q = (const float*)d_in[0];
    const float* K = (const float*)d_in[1];
    const float* V = (const float*)d_in[2];
    float* Op = (float*)d_out;

    const size_t halfBytes = (size_t)NB * HH * SS * EE * 2; // 8 MB
    if (ws_size >= 2 * halfBytes) {
        unsigned short* Kht = (unsigned short*)d_ws;
        unsigned short* Vht = (unsigned short*)((char*)d_ws + halfBytes);
        hipLaunchKernelGGL(prepK, dim3(NB * HH * NT), dim3(256), 0, stream, K, Kht);
        hipLaunchKernelGGL(prepV, dim3(NB * HH * NT), dim3(256), 0, stream, V, Vht);
        hipLaunchKernelGGL(fattn2, dim3(NWG), dim3(256), 0, stream, Kht, Vht, Q, Op);
    } else {
        hipLaunchKernelGGL(fattn1, dim3(NB * HH * (LL / 64)), dim3(256), 0, stream, Q, K, V, Op);
    }
}

// Round 4
// 80.322 us; speedup vs baseline: 1.3148x; 1.1243x over previous
//
#include <hip/hip_runtime.h>
#include <hip/hip_bf16.h>
#include <string.h>

// FullAttention fwd: B=2, L=S=2048, H=16, E=D=64, fp32 in/out.
// R4: R3 structure (32x32x16 f16 MFMA, swapped QK^T, in-register softmax +
// P->B-frag via cvt_pkrtz + permlane32_swap) with the l double-count fixed:
// l is accumulated as a per-lane PARTIAL (own 32 s-values) and combined by
// ONE permlane32_swap in the epilogue. Prep kernels fused into one launch.

#define NB 2
#define LL 2048
#define SS 2048
#define HH 16
#define EE 64
#define DD 64
#define KVB 64
#define NT (SS / KVB) /* 32 */
#define QBLK 128
#define NWG (NB * HH * (LL / QBLK)) /* 512 */

typedef _Float16 f16x8 __attribute__((ext_vector_type(8)));
typedef float f32x4 __attribute__((ext_vector_type(4)));
typedef float f32x16 __attribute__((ext_vector_type(16)));
typedef unsigned uint2v __attribute__((ext_vector_type(2)));
typedef unsigned uint4v __attribute__((ext_vector_type(4)));
typedef const __attribute__((address_space(1))) void* gas_p;
typedef __attribute__((address_space(3))) void* las_p;

__device__ __forceinline__ unsigned pk2h(float a, float b) {
    auto h = __builtin_amdgcn_cvt_pkrtz(a, b);
    unsigned u;
    __builtin_memcpy(&u, &h, 4);
    return u;
}

__device__ __forceinline__ void gll16(const void* g, void* l) {
    __builtin_amdgcn_global_load_lds((gas_p)g, (las_p)l, 16, 0, 0);
}

// permlane32_swap(a,b):
// res[0]: lanes<32 = a(own), lanes>=32 = b[lane-32]
// res[1]: lanes<32 = a[lane+32], lanes>=32 = b(own)
__device__ __forceinline__ uint2v plswap(unsigned a, unsigned b) {
#if defined(__has_builtin) && __has_builtin(__builtin_amdgcn_permlane32_swap)
    return __builtin_amdgcn_permlane32_swap(a, b, false, false);
#else
    unsigned ax = (unsigned)__shfl_xor((int)a, 32);
    unsigned bx = (unsigned)__shfl_xor((int)b, 32);
    int l32 = (int)(threadIdx.x & 32);
    uint2v r;
    r[0] = l32 ? bx : a;
    r[1] = l32 ? b : ax;
    return r;
#endif
}

__device__ __forceinline__ float fbits(unsigned u) {
    float f; __builtin_memcpy(&f, &u, 4); return f;
}
__device__ __forceinline__ unsigned ubits(float f) {
    unsigned u; __builtin_memcpy(&u, &f, 4); return u;
}
__device__ __forceinline__ float xmax32(float x) {
    uint2v r = plswap(ubits(x), ubits(x));
    return fmaxf(fbits(r[0]), fbits(r[1]));
}
__device__ __forceinline__ float xsum32(float x) {
    uint2v r = plswap(ubits(x), ubits(x));
    return fbits(r[0]) + fbits(r[1]);
}

// ---------------- fused prep: K -> f16 tile image, V -> V^T f16 tile image --
// Kh tile (8KB): byte (s*128 + e*2) ^ ((s&7)<<4) holds f16 K[s0+s][e]
// Vth tile (8KB): byte (d*128 + s*2) ^ ((d&7)<<4) holds f16 V[s0+s][d]
__global__ __launch_bounds__(256) void prepKV(const float* __restrict__ K,
                                              const float* __restrict__ V,
                                              unsigned short* __restrict__ Kh,
                                              unsigned short* __restrict__ Vth) {
    const int NTILE = NB * HH * NT; // 1024
    const bool isV = blockIdx.x >= NTILE;
    const int tile = blockIdx.x & (NTILE - 1);
    const int it = tile & (NT - 1);
    const int bh = tile >> 5;
    const int b = bh >> 4, h = bh & 15;
    const int t = threadIdx.x;

    if (!isV) {
        const int s = t >> 2, ec = t & 3;
        const float* src = K + (((size_t)b * SS + it * KVB + s) * HH + h) * EE + ec * 16;
        f32x4 x0 = ((const f32x4*)src)[0];
        f32x4 x1 = ((const f32x4*)src)[1];
        f32x4 x2 = ((const f32x4*)src)[2];
        f32x4 x3 = ((const f32x4*)src)[3];
        uint4v c0, c1;
        c0.x = pk2h(x0[0], x0[1]); c0.y = pk2h(x0[2], x0[3]);
        c0.z = pk2h(x1[0], x1[1]); c0.w = pk2h(x1[2], x1[3]);
        c1.x = pk2h(x2[0], x2[1]); c1.y = pk2h(x2[2], x2[3]);
        c1.z = pk2h(x3[0], x3[1]); c1.w = pk2h(x3[2], x3[3]);
        char* dst = (char*)Kh + (size_t)tile * 8192;
        const int sw = (s & 7) << 4;
        *(uint4v*)(dst + ((s * 128 + ec * 32) ^ sw)) = c0;
        *(uint4v*)(dst + ((s * 128 + ec * 32 + 16) ^ sw)) = c1;
    } else {
        __shared__ float Vt[64 * 68];
        {
            const int s = t >> 2, dc = t & 3;
            const float* src = V + (((size_t)b * SS + it * KVB + s) * HH + h) * DD + dc * 16;
            f32x4 x0 = ((const f32x4*)src)[0];
            f32x4 x1 = ((const f32x4*)src)[1];
            f32x4 x2 = ((const f32x4*)src)[2];
            f32x4 x3 = ((const f32x4*)src)[3];
            float* row = Vt + s * 68 + dc * 16;
            ((f32x4*)row)[0] = x0; ((f32x4*)row)[1] = x1;
            ((f32x4*)row)[2] = x2; ((f32x4*)row)[3] = x3;
        }
        __syncthreads();
        {
            const int d = t >> 2, sc = t & 3;
            float w[16];
#pragma unroll
            for (int j = 0; j < 16; ++j) w[j] = Vt[(sc * 16 + j) * 68 + d];
            uint4v c0, c1;
            c0.x = pk2h(w[0], w[1]); c0.y = pk2h(w[2], w[3]);
            c0.z = pk2h(w[4], w[5]); c0.w = pk2h(w[6], w[7]);
            c1.x = pk2h(w[8], w[9]); c1.y = pk2h(w[10], w[11]);
            c1.z = pk2h(w[12], w[13]); c1.w = pk2h(w[14], w[15]);
            char* dst = (char*)Vth + (size_t)tile * 8192;
            const int sw = (d & 7) << 4;
            *(uint4v*)(dst + ((d * 128 + sc * 32) ^ sw)) = c0;
            *(uint4v*)(dst + ((d * 128 + sc * 32 + 16) ^ sw)) = c1;
        }
    }
}

// ---------------- main attention kernel (32x32, T12) ----------------
__global__ __launch_bounds__(256) void fattn3(const unsigned short* __restrict__ Kh,
                                              const unsigned short* __restrict__ Vth,
                                              const float* __restrict__ Q,
                                              float* __restrict__ O) {
    __shared__ __align__(16) char K0s[8192], K1s[8192], V0s[8192], V1s[8192];

    const int tid = threadIdx.x;
    const int lane = tid & 63;
    const int wid = tid >> 6;      // 0..3
    const int ln = lane & 31;      // q (and A-frag row)
    const int hi = lane >> 5;      // k-half selector

    const int bid0 = blockIdx.x;
    const int bid = (bid0 & 7) * (NWG >> 3) + (bid0 >> 3); // bijective XCD swizzle
    const int bh = bid >> 4;
    const int qt = bid & 15;
    const int b = bh >> 4, h = bh & 15;
    const int qrow = qt * QBLK + wid * 32 + ln;

    // ---- Q B-frags: qf[ks] holds Q^T[k=e][n=q]: n=ln, e = ks*16 + hi*8 + j ----
    const float qs = 0.125f * 1.44269504088896340736f; // scale * log2(e)
    const float* qptr = Q + (((size_t)b * LL + qrow) * HH + h) * EE + hi * 8;
    f16x8 qf[4];
#pragma unroll
    for (int ks = 0; ks < 4; ++ks) {
        f32x4 a0 = *(const f32x4*)(qptr + ks * 16);
        f32x4 a1 = *(const f32x4*)(qptr + ks * 16 + 4);
        union { f16x8 v; unsigned u[4]; } cv;
        cv.u[0] = pk2h(a0[0] * qs, a0[1] * qs);
        cv.u[1] = pk2h(a0[2] * qs, a0[3] * qs);
        cv.u[2] = pk2h(a1[0] * qs, a1[1] * qs);
        cv.u[3] = pk2h(a1[2] * qs, a1[3] * qs);
        qf[ks] = cv.v;
    }

    f32x16 o0, o1;
#pragma unroll
    for (int i = 0; i < 16; ++i) { o0[i] = 0.f; o1[i] = 0.f; }
    float m = -1e30f, l = 0.f; // l is a PER-LANE PARTIAL (own 32 s-values)

    const char* Kg = (const char*)Kh + (size_t)bh * (NT * 8192);
    const char* Vg = (const char*)Vth + (size_t)bh * (NT * 8192);

    auto STAGE = [&](int it, char* Ks, char* Vs) {
        const size_t off = (size_t)it * 8192 + wid * 2048 + lane * 16;
        gll16(Kg + off, Ks + wid * 2048);
        gll16(Kg + off + 1024, Ks + wid * 2048 + 1024);
        gll16(Vg + off, Vs + wid * 2048);
        gll16(Vg + off + 1024, Vs + wid * 2048 + 1024);
    };

    const int swA = (ln & 7) << 4;
    auto COMPUTE = [&](const char* Ks, const char* Vs) {
        // ---- QK^T: st0 = S^T[s=0..31][q], st1 = S^T[s=32..63][q] ----
        f32x16 st0, st1;
#pragma unroll
        for (int i = 0; i < 16; ++i) { st0[i] = 0.f; st1[i] = 0.f; }
        __builtin_amdgcn_s_setprio(1);
#pragma unroll
        for (int ks = 0; ks < 4; ++ks) {
            f16x8 k0 = *(const f16x8*)(Ks + ((ln * 128 + ks * 32 + hi * 16) ^ swA));
            f16x8 k1 = *(const f16x8*)(Ks + (((32 + ln) * 128 + ks * 32 + hi * 16) ^ swA));
            st0 = __builtin_amdgcn_mfma_f32_32x32x16_f16(k0, qf[ks], st0, 0, 0, 0);
            st1 = __builtin_amdgcn_mfma_f32_32x32x16_f16(k1, qf[ks], st1, 0, 0, 0);
        }
        __builtin_amdgcn_s_setprio(0);

        // ---- softmax (log2 domain): lane owns 32 of 64 s-values for q=ln ----
        float x0 = fmaxf(st0[0], st1[0]), x1 = fmaxf(st0[1], st1[1]);
        float x2 = fmaxf(st0[2], st1[2]), x3 = fmaxf(st0[3], st1[3]);
#pragma unroll
        for (int r = 4; r < 16; r += 4) {
            x0 = fmaxf(x0, fmaxf(st0[r], st1[r]));
            x1 = fmaxf(x1, fmaxf(st0[r + 1], st1[r + 1]));
            x2 = fmaxf(x2, fmaxf(st0[r + 2], st1[r + 2]));
            x3 = fmaxf(x3, fmaxf(st0[r + 3], st1[r + 3]));
        }
        float pmax = fmaxf(fmaxf(x0, x1), fmaxf(x2, x3));
        pmax = xmax32(pmax); // full 64-s row max (uniform across partner pair)

        if (!__all(pmax - m <= 8.0f)) { // defer-max (THR=8 in log2 domain)
            const float mn = fmaxf(m, pmax);
            const float al = exp2f(m - mn);
            l *= al; m = mn;
#pragma unroll
            for (int i = 0; i < 16; ++i) { o0[i] *= al; o1[i] *= al; }
        }
        float t0 = 0.f, t1 = 0.f, t2 = 0.f, t3 = 0.f;
#pragma unroll
        for (int r = 0; r < 16; r += 4) {
            st0[r] = exp2f(st0[r] - m);     st1[r] = exp2f(st1[r] - m);
            st0[r + 1] = exp2f(st0[r + 1] - m); st1[r + 1] = exp2f(st1[r + 1] - m);
            st0[r + 2] = exp2f(st0[r + 2] - m); st1[r + 2] = exp2f(st1[r + 2] - m);
            st0[r + 3] = exp2f(st0[r + 3] - m); st1[r + 3] = exp2f(st1[r + 3] - m);
            t0 += st0[r] + st1[r];
            t1 += st0[r + 1] + st1[r + 1];
            t2 += st0[r + 2] + st1[r + 2];
            t3 += st0[r + 3] + st1[r + 3];
        }
        l += (t0 + t1) + (t2 + t3); // per-lane partial; combined once at end

        // ---- P -> PV B-frags in-register (cvt_pk + permlane32_swap, T12) ----
        f16x8 pb[4];
        {
            uint2v r0 = plswap(pk2h(st0[0], st0[1]), pk2h(st0[4], st0[5]));
            uint2v r1 = plswap(pk2h(st0[2], st0[3]), pk2h(st0[6], st0[7]));
            union { f16x8 v; unsigned u[4]; } w;
            w.u[0] = r0[0]; w.u[1] = r1[0]; w.u[2] = r0[1]; w.u[3] = r1[1];
            pb[0] = w.v;
            uint2v r2 = plswap(pk2h(st0[8], st0[9]), pk2h(st0[12], st0[13]));
            uint2v r3 = plswap(pk2h(st0[10], st0[11]), pk2h(st0[14], st0[15]));
            w.u[0] = r2[0]; w.u[1] = r3[0]; w.u[2] = r2[1]; w.u[3] = r3[1];
            pb[1] = w.v;
        }
        {
            uint2v r0 = plswap(pk2h(st1[0], st1[1]), pk2h(st1[4], st1[5]));
            uint2v r1 = plswap(pk2h(st1[2], st1[3]), pk2h(st1[6], st1[7]));
            union { f16x8 v; unsigned u[4]; } w;
            w.u[0] = r0[0]; w.u[1] = r1[0]; w.u[2] = r0[1]; w.u[3] = r1[1];
            pb[2] = w.v;
            uint2v r2 = plswap(pk2h(st1[8], st1[9]), pk2h(st1[12], st1[13]));
            uint2v r3 = plswap(pk2h(st1[10], st1[11]), pk2h(st1[14], st1[15]));
            w.u[0] = r2[0]; w.u[1] = r3[0]; w.u[2] = r2[1]; w.u[3] = r3[1];
            pb[3] = w.v;
        }

        // ---- PV: O^T[d][q] += V^T[d][s] * P^T[s][q] ----
        __builtin_amdgcn_s_setprio(1);
#pragma unroll
        for (int ks = 0; ks < 4; ++ks) {
            f16x8 v0 = *(const f16x8*)(Vs + ((ln * 128 + ks * 32 + hi * 16) ^ swA));
            f16x8 v1 = *(const f16x8*)(Vs + (((32 + ln) * 128 + ks * 32 + hi * 16) ^ swA));
            o0 = __builtin_amdgcn_mfma_f32_32x32x16_f16(v0, pb[ks], o0, 0, 0, 0);
            o1 = __builtin_amdgcn_mfma_f32_32x32x16_f16(v1, pb[ks], o1, 0, 0, 0);
        }
        __builtin_amdgcn_s_setprio(0);
    };

    STAGE(0, K0s, V0s);
    __syncthreads();
    for (int it = 0; it < NT; it += 2) {
        if (it + 1 < NT) STAGE(it + 1, K1s, V1s);
        COMPUTE(K0s, V0s);
        __syncthreads();
        if (it + 2 < NT) STAGE(it + 2, K0s, V0s);
        COMPUTE(K1s, V1s);
        __syncthreads();
    }

    // ---- epilogue: combine l across partner halves ONCE, normalize, store ----
    l = xsum32(l);
    const float invl = 1.f / l;
    float* optr = O + (((size_t)b * LL + qrow) * HH + h) * DD;
#pragma unroll
    for (int t = 0; t < 4; ++t) {
        f32x4 w;
        w[0] = o0[4 * t] * invl; w[1] = o0[4 * t + 1] * invl;
        w[2] = o0[4 * t + 2] * invl; w[3] = o0[4 * t + 3] * invl;
        *(f32x4*)(optr + t * 8 + hi * 4) = w;
    }
#pragma unroll
    for (int t = 0; t < 4; ++t) {
        f32x4 w;
        w[0] = o1[4 * t] * invl; w[1] = o1[4 * t + 1] * invl;
        w[2] = o1[4 * t + 2] * invl; w[3] = o1[4 * t + 3] * invl;
        *(f32x4*)(optr + 32 + t * 8 + hi * 4) = w;
    }
}

// ---------------- fallback (R1 kernel, used if ws too small) ----------------
typedef unsigned u2f __attribute__((ext_vector_type(2)));
__global__ __launch_bounds__(256) void fattn1(const float* __restrict__ Q,
                                              const float* __restrict__ K,
                                              const float* __restrict__ V,
                                              float* __restrict__ O) {
    __shared__ __align__(16) short Klds[KVB * 64];
    __shared__ __align__(16) short Vtlds[64 * KVB];
    __shared__ __align__(16) short Plds[4][16 * 64];

    const int tid = threadIdx.x;
    const int lane = tid & 63;
    const int wid = tid >> 6;
    const int g = (lane >> 4) & 3;
    const int c = lane & 15;

    const int bid = blockIdx.x;
    const int bh = bid >> 5;
    const int qt = bid & 31;
    const int b = bh >> 4;
    const int h = bh & 15;
    const int q0 = qt * 64;

    const int qrow = q0 + wid * 16 + c;
    const float* qptr = Q + (((size_t)b * LL + qrow) * HH + h) * EE;
    const float qs = 0.125f * 1.44269504088896340736f;
    f16x8 qf[2];
#pragma unroll
    for (int kk = 0; kk < 2; ++kk) {
        f32x4 a0 = *(const f32x4*)(qptr + kk * 32 + g * 8);
        f32x4 a1 = *(const f32x4*)(qptr + kk * 32 + g * 8 + 4);
        union { f16x8 v; unsigned u[4]; } cv;
        cv.u[0] = pk2h(a0[0] * qs, a0[1] * qs);
        cv.u[1] = pk2h(a0[2] * qs, a0[3] * qs);
        cv.u[2] = pk2h(a1[0] * qs, a1[1] * qs);
        cv.u[3] = pk2h(a1[2] * qs, a1[3] * qs);
        qf[kk] = cv.v;
    }

    f32x4 osacc[4];
    const f32x4 fzero = {0.f, 0.f, 0.f, 0.f};
#pragma unroll
    for (int i = 0; i < 4; ++i) osacc[i] = fzero;
    float m_run = -1e30f;
    float l_run = 0.f;

    const int km = tid & 15;
    const int kr = tid >> 4;

    for (int it = 0; it < NT; ++it) {
        const int s_glob = it * KVB;
        f32x4 kreg[4];
#pragma unroll
        for (int p = 0; p < 4; ++p) {
            int s = kr + p * 16;
            kreg[p] = *(const f32x4*)(K + (((size_t)b * SS + s_glob + s) * HH + h) * EE + km * 4);
        }
        f32x4 vreg[4];
#pragma unroll
        for (int p = 0; p < 4; ++p) {
            int s = kr * 4 + p;
            vreg[p] = *(const f32x4*)(V + (((size_t)b * SS + s_glob + s) * HH + h) * DD + km * 4);
        }
        __syncthreads();
#pragma unroll
        for (int p = 0; p < 4; ++p) {
            int s = kr + p * 16;
            u2f w;
            w.x = pk2h(kreg[p][0], kreg[p][1]);
            w.y = pk2h(kreg[p][2], kreg[p][3]);
            int byte = (s * 128 + km * 8) ^ ((s & 7) << 4);
            *(u2f*)((char*)Klds + byte) = w;
        }
#pragma unroll
        for (int i = 0; i < 4; ++i) {
            int d = km * 4 + i;
            u2f w;
            w.x = pk2h(vreg[0][i], vreg[1][i]);
            w.y = pk2h(vreg[2][i], vreg[3][i]);
            int byte = (d * 128 + kr * 8) ^ ((d & 7) << 4);
            *(u2f*)((char*)Vtlds + byte) = w;
        }
        __syncthreads();

        f32x4 stv[4];
#pragma unroll
        for (int fr = 0; fr < 4; ++fr) stv[fr] = fzero;
#pragma unroll
        for (int fr = 0; fr < 4; ++fr) {
            int s = fr * 16 + c;
            f16x8 kf0 = *(const f16x8*)((const char*)Klds + ((s * 128 + 16 * g) ^ ((s & 7) << 4)));
            stv[fr] = __builtin_amdgcn_mfma_f32_16x16x32_f16(kf0, qf[0], stv[fr], 0, 0, 0);
            f16x8 kf1 = *(const f16x8*)((const char*)Klds + ((s * 128 + 64 + 16 * g) ^ ((s & 7) << 4)));
            stv[fr] = __builtin_amdgcn_mfma_f32_16x16x32_f16(kf1, qf[1], stv[fr], 0, 0, 0);
        }

        float pmax = stv[0][0];
#pragma unroll
        for (int fr = 0; fr < 4; ++fr)
#pragma unroll
            for (int r = 0; r < 4; ++r) pmax = fmaxf(pmax, stv[fr][r]);
        pmax = fmaxf(pmax, __shfl_xor(pmax, 16));
        pmax = fmaxf(pmax, __shfl_xor(pmax, 32));
        float mnew = fmaxf(m_run, pmax);
        float alpha = exp2f(m_run - mnew);
        float tsum = 0.f;
#pragma unroll
        for (int fr = 0; fr < 4; ++fr)
#pragma unroll
            for (int r = 0; r < 4; ++r) {
                float e = exp2f(stv[fr][r] - mnew);
                stv[fr][r] = e;
                tsum += e;
            }
        tsum += __shfl_xor(tsum, 16);
        tsum += __shfl_xor(tsum, 32);
        l_run = l_run * alpha + tsum;
        m_run = mnew;
#pragma unroll
        for (int fr = 0; fr < 4; ++fr)
#pragma unroll
            for (int r = 0; r < 4; ++r) osacc[fr][r] *= alpha;

        short* plb = &Plds[wid][0];
#pragma unroll
        for (int fr = 0; fr < 4; ++fr) {
            u2f w;
            w.x = pk2h(stv[fr][0], stv[fr][1]);
            w.y = pk2h(stv[fr][2], stv[fr][3]);
            int byte = (c * 128 + fr * 32 + g * 8) ^ ((c & 7) << 4);
            *(u2f*)((char*)plb + byte) = w;
        }
        f16x8 pb0 = *(const f16x8*)((const char*)plb + ((c * 128 + 16 * g) ^ ((c & 7) << 4)));
        f16x8 pb1 = *(const f16x8*)((const char*)plb + ((c * 128 + 64 + 16 * g) ^ ((c & 7) << 4)));

#pragma unroll
        for (int fr = 0; fr < 4; ++fr) {
            int d = fr * 16 + c;
            f16x8 vf0 = *(const f16x8*)((const char*)Vtlds + ((d * 128 + 16 * g) ^ ((d & 7) << 4)));
            osacc[fr] = __builtin_amdgcn_mfma_f32_16x16x32_f16(vf0, pb0, osacc[fr], 0, 0, 0);
            f16x8 vf1 = *(const f16x8*)((const char*)Vtlds + ((d * 128 + 64 + 16 * g) ^ ((d & 7) << 4)));
            osacc[fr] = __builtin_amdgcn_mfma_f32_16x16x32_f16(vf1, pb1, osacc[fr], 0, 0, 0);
        }
    }

    float invl = 1.f / l_run;
    float* optr = O + (((size_t)b * LL + qrow) * HH + h) * DD;
#pragma unroll
    for (int fr = 0; fr < 4; ++fr) {
        f32x4 o;
        o[0] = osacc[fr][0] * invl;
        o[1] = osacc[fr][1] * invl;
        o[2] = osacc[fr][2] * invl;
        o[3] = osacc[fr][3] * invl;
        *(f32x4*)(optr + fr * 16 + g * 4) = o;
    }
}

extern "C" void kernel_launch(void* const* d_in, const int* in_sizes, int n_in,
                              void* d_out, int out_size, void* d_ws, size_t ws_size,
                              hipStream_t stream) {
    const float* Q = (const float*)d_in[0];
    const float* K = (const float*)d_in[1];
    const float* V = (const float*)d_in[2];
    float* Op = (float*)d_out;

    const size_t halfBytes = (size_t)NB * HH * SS * EE * 2; // 8 MB
    if (ws_size >= 2 * halfBytes) {
        unsigned short* Kht = (unsigned short*)d_ws;
        unsigned short* Vht = (unsigned short*)((char*)d_ws + halfBytes);
        hipLaunchKernelGGL(prepKV, dim3(2 * NB * HH * NT), dim3(256), 0, stream, K, V, Kht, Vht);
        hipLaunchKernelGGL(fattn3, dim3(NWG), dim3(256), 0, stream, Kht, Vht, Q, Op);
    } else {
        hipLaunchKernelGGL(fattn1, dim3(NB * HH * (LL / 64)), dim3(256), 0, stream, Q, K, V, Op);
    }
}

// Round 5
// 68.436 us; speedup vs baseline: 1.5431x; 1.1737x over previous
//
#include <hip/hip_runtime.h>
#include <hip/hip_bf16.h>
#include <string.h>

// FullAttention fwd: B=2, L=S=2048, H=16, E=D=64, fp32 in/out.
// R5: R4 structure (32x32x16 f16 MFMA, swapped QK^T, in-register softmax +
// P->B-frag via cvt_pkrtz + permlane32_swap) with:
//  - raw v_exp_f32 (__builtin_amdgcn_exp2f) instead of OCML exp2f libcall
//  - speculative exp: tiles>0 compute e=exp2(st-m_old) immediately (parallel
//    with the max tree); rare rescale multiplies by exp2(m-mn) (exact pow2).
//    Tile 0 peeled, classic max-first path.

#define NB 2
#define LL 2048
#define SS 2048
#define HH 16
#define EE 64
#define DD 64
#define KVB 64
#define NT (SS / KVB) /* 32 */
#define QBLK 128
#define NWG (NB * HH * (LL / QBLK)) /* 512 */

typedef _Float16 f16x8 __attribute__((ext_vector_type(8)));
typedef float f32x4 __attribute__((ext_vector_type(4)));
typedef float f32x16 __attribute__((ext_vector_type(16)));
typedef unsigned uint2v __attribute__((ext_vector_type(2)));
typedef unsigned uint4v __attribute__((ext_vector_type(4)));
typedef const __attribute__((address_space(1))) void* gas_p;
typedef __attribute__((address_space(3))) void* las_p;

__device__ __forceinline__ unsigned pk2h(float a, float b) {
    auto h = __builtin_amdgcn_cvt_pkrtz(a, b);
    unsigned u;
    __builtin_memcpy(&u, &h, 4);
    return u;
}

// raw v_exp_f32 (2^x), no libcall edge handling
__device__ __forceinline__ float fexp2(float x) {
#if defined(__has_builtin) && __has_builtin(__builtin_amdgcn_exp2f)
    return __builtin_amdgcn_exp2f(x);
#else
    return exp2f(x);
#endif
}

__device__ __forceinline__ void gll16(const void* g, void* l) {
    __builtin_amdgcn_global_load_lds((gas_p)g, (las_p)l, 16, 0, 0);
}

// permlane32_swap(a,b):
// res[0]: lanes<32 = a(own), lanes>=32 = b[lane-32]
// res[1]: lanes<32 = a[lane+32], lanes>=32 = b(own)
__device__ __forceinline__ uint2v plswap(unsigned a, unsigned b) {
#if defined(__has_builtin) && __has_builtin(__builtin_amdgcn_permlane32_swap)
    return __builtin_amdgcn_permlane32_swap(a, b, false, false);
#else
    unsigned ax = (unsigned)__shfl_xor((int)a, 32);
    unsigned bx = (unsigned)__shfl_xor((int)b, 32);
    int l32 = (int)(threadIdx.x & 32);
    uint2v r;
    r[0] = l32 ? bx : a;
    r[1] = l32 ? b : ax;
    return r;
#endif
}

__device__ __forceinline__ float fbits(unsigned u) {
    float f; __builtin_memcpy(&f, &u, 4); return f;
}
__device__ __forceinline__ unsigned ubits(float f) {
    unsigned u; __builtin_memcpy(&u, &f, 4); return u;
}
__device__ __forceinline__ float xmax32(float x) {
    uint2v r = plswap(ubits(x), ubits(x));
    return fmaxf(fbits(r[0]), fbits(r[1]));
}
__device__ __forceinline__ float xsum32(float x) {
    uint2v r = plswap(ubits(x), ubits(x));
    return fbits(r[0]) + fbits(r[1]);
}

// ---------------- fused prep: K -> f16 tile image, V -> V^T f16 tile image --
// Kh tile (8KB): byte (s*128 + e*2) ^ ((s&7)<<4) holds f16 K[s0+s][e]
// Vth tile (8KB): byte (d*128 + s*2) ^ ((d&7)<<4) holds f16 V[s0+s][d]
__global__ __launch_bounds__(256) void prepKV(const float* __restrict__ K,
                                              const float* __restrict__ V,
                                              unsigned short* __restrict__ Kh,
                                              unsigned short* __restrict__ Vth) {
    const int NTILE = NB * HH * NT; // 1024
    const bool isV = blockIdx.x >= NTILE;
    const int tile = blockIdx.x & (NTILE - 1);
    const int it = tile & (NT - 1);
    const int bh = tile >> 5;
    const int b = bh >> 4, h = bh & 15;
    const int t = threadIdx.x;

    if (!isV) {
        const int s = t >> 2, ec = t & 3;
        const float* src = K + (((size_t)b * SS + it * KVB + s) * HH + h) * EE + ec * 16;
        f32x4 x0 = ((const f32x4*)src)[0];
        f32x4 x1 = ((const f32x4*)src)[1];
        f32x4 x2 = ((const f32x4*)src)[2];
        f32x4 x3 = ((const f32x4*)src)[3];
        uint4v c0, c1;
        c0.x = pk2h(x0[0], x0[1]); c0.y = pk2h(x0[2], x0[3]);
        c0.z = pk2h(x1[0], x1[1]); c0.w = pk2h(x1[2], x1[3]);
        c1.x = pk2h(x2[0], x2[1]); c1.y = pk2h(x2[2], x2[3]);
        c1.z = pk2h(x3[0], x3[1]); c1.w = pk2h(x3[2], x3[3]);
        char* dst = (char*)Kh + (size_t)tile * 8192;
        const int sw = (s & 7) << 4;
        *(uint4v*)(dst + ((s * 128 + ec * 32) ^ sw)) = c0;
        *(uint4v*)(dst + ((s * 128 + ec * 32 + 16) ^ sw)) = c1;
    } else {
        __shared__ float Vt[64 * 68];
        {
            const int s = t >> 2, dc = t & 3;
            const float* src = V + (((size_t)b * SS + it * KVB + s) * HH + h) * DD + dc * 16;
            f32x4 x0 = ((const f32x4*)src)[0];
            f32x4 x1 = ((const f32x4*)src)[1];
            f32x4 x2 = ((const f32x4*)src)[2];
            f32x4 x3 = ((const f32x4*)src)[3];
            float* row = Vt + s * 68 + dc * 16;
            ((f32x4*)row)[0] = x0; ((f32x4*)row)[1] = x1;
            ((f32x4*)row)[2] = x2; ((f32x4*)row)[3] = x3;
        }
        __syncthreads();
        {
            const int d = t >> 2, sc = t & 3;
            float w[16];
#pragma unroll
            for (int j = 0; j < 16; ++j) w[j] = Vt[(sc * 16 + j) * 68 + d];
            uint4v c0, c1;
            c0.x = pk2h(w[0], w[1]); c0.y = pk2h(w[2], w[3]);
            c0.z = pk2h(w[4], w[5]); c0.w = pk2h(w[6], w[7]);
            c1.x = pk2h(w[8], w[9]); c1.y = pk2h(w[10], w[11]);
            c1.z = pk2h(w[12], w[13]); c1.w = pk2h(w[14], w[15]);
            char* dst = (char*)Vth + (size_t)tile * 8192;
            const int sw = (d & 7) << 4;
            *(uint4v*)(dst + ((d * 128 + sc * 32) ^ sw)) = c0;
            *(uint4v*)(dst + ((d * 128 + sc * 32 + 16) ^ sw)) = c1;
        }
    }
}

// ---------------- main attention kernel (32x32, T12, speculative exp) ------
__global__ __launch_bounds__(256) void fattn3(const unsigned short* __restrict__ Kh,
                                              const unsigned short* __restrict__ Vth,
                                              const float* __restrict__ Q,
                                              float* __restrict__ O) {
    __shared__ __align__(16) char K0s[8192], K1s[8192], V0s[8192], V1s[8192];

    const int tid = threadIdx.x;
    const int lane = tid & 63;
    const int wid = tid >> 6;      // 0..3
    const int ln = lane & 31;      // q (and A-frag row)
    const int hi = lane >> 5;      // k-half selector

    const int bid0 = blockIdx.x;
    const int bid = (bid0 & 7) * (NWG >> 3) + (bid0 >> 3); // bijective XCD swizzle
    const int bh = bid >> 4;
    const int qt = bid & 15;
    const int b = bh >> 4, h = bh & 15;
    const int qrow = qt * QBLK + wid * 32 + ln;

    // ---- Q B-frags: qf[ks] holds Q^T[k=e][n=q]: n=ln, e = ks*16 + hi*8 + j ----
    const float qs = 0.125f * 1.44269504088896340736f; // scale * log2(e)
    const float* qptr = Q + (((size_t)b * LL + qrow) * HH + h) * EE + hi * 8;
    f16x8 qf[4];
#pragma unroll
    for (int ks = 0; ks < 4; ++ks) {
        f32x4 a0 = *(const f32x4*)(qptr + ks * 16);
        f32x4 a1 = *(const f32x4*)(qptr + ks * 16 + 4);
        union { f16x8 v; unsigned u[4]; } cv;
        cv.u[0] = pk2h(a0[0] * qs, a0[1] * qs);
        cv.u[1] = pk2h(a0[2] * qs, a0[3] * qs);
        cv.u[2] = pk2h(a1[0] * qs, a1[1] * qs);
        cv.u[3] = pk2h(a1[2] * qs, a1[3] * qs);
        qf[ks] = cv.v;
    }

    f32x16 o0, o1;
#pragma unroll
    for (int i = 0; i < 16; ++i) { o0[i] = 0.f; o1[i] = 0.f; }
    float m = -1e30f, l = 0.f; // l is a PER-LANE PARTIAL (own 32 s-values)

    const char* Kg = (const char*)Kh + (size_t)bh * (NT * 8192);
    const char* Vg = (const char*)Vth + (size_t)bh * (NT * 8192);

    auto STAGE = [&](int it, char* Ks, char* Vs) {
        const size_t off = (size_t)it * 8192 + wid * 2048 + lane * 16;
        gll16(Kg + off, Ks + wid * 2048);
        gll16(Kg + off + 1024, Ks + wid * 2048 + 1024);
        gll16(Vg + off, Vs + wid * 2048);
        gll16(Vg + off + 1024, Vs + wid * 2048 + 1024);
    };

    const int swA = (ln & 7) << 4;
    auto COMPUTE = [&](const char* Ks, const char* Vs, bool FIRST) {
        // ---- QK^T: st0 = S^T[s=0..31][q], st1 = S^T[s=32..63][q] ----
        f32x16 st0, st1;
#pragma unroll
        for (int i = 0; i < 16; ++i) { st0[i] = 0.f; st1[i] = 0.f; }
        __builtin_amdgcn_s_setprio(1);
#pragma unroll
        for (int ks = 0; ks < 4; ++ks) {
            f16x8 k0 = *(const f16x8*)(Ks + ((ln * 128 + ks * 32 + hi * 16) ^ swA));
            f16x8 k1 = *(const f16x8*)(Ks + (((32 + ln) * 128 + ks * 32 + hi * 16) ^ swA));
            st0 = __builtin_amdgcn_mfma_f32_32x32x16_f16(k0, qf[ks], st0, 0, 0, 0);
            st1 = __builtin_amdgcn_mfma_f32_32x32x16_f16(k1, qf[ks], st1, 0, 0, 0);
        }
        __builtin_amdgcn_s_setprio(0);

        if (FIRST) {
            // ---- classic: max first (m is -1e30, exp(st-m) would overflow) ----
            float x0 = fmaxf(st0[0], st1[0]), x1 = fmaxf(st0[1], st1[1]);
            float x2 = fmaxf(st0[2], st1[2]), x3 = fmaxf(st0[3], st1[3]);
#pragma unroll
            for (int r = 4; r < 16; r += 4) {
                x0 = fmaxf(x0, fmaxf(st0[r], st1[r]));
                x1 = fmaxf(x1, fmaxf(st0[r + 1], st1[r + 1]));
                x2 = fmaxf(x2, fmaxf(st0[r + 2], st1[r + 2]));
                x3 = fmaxf(x3, fmaxf(st0[r + 3], st1[r + 3]));
            }
            float pmax = fmaxf(fmaxf(x0, x1), fmaxf(x2, x3));
            m = xmax32(pmax);
            float t0 = 0.f, t1 = 0.f, t2 = 0.f, t3 = 0.f;
#pragma unroll
            for (int r = 0; r < 16; r += 4) {
                st0[r] = fexp2(st0[r] - m);     st1[r] = fexp2(st1[r] - m);
                st0[r + 1] = fexp2(st0[r + 1] - m); st1[r + 1] = fexp2(st1[r + 1] - m);
                st0[r + 2] = fexp2(st0[r + 2] - m); st1[r + 2] = fexp2(st1[r + 2] - m);
                st0[r + 3] = fexp2(st0[r + 3] - m); st1[r + 3] = fexp2(st1[r + 3] - m);
                t0 += st0[r] + st1[r];
                t1 += st0[r + 1] + st1[r + 1];
                t2 += st0[r + 2] + st1[r + 2];
                t3 += st0[r + 3] + st1[r + 3];
            }
            l = (t0 + t1) + (t2 + t3);
        } else {
            // ---- speculative: exp with OLD m immediately; max tree in parallel.
            // Rescale (rare) multiplies by exp2(m-mn) — exact power of 2.
            f32x16 e0, e1;
#pragma unroll
            for (int r = 0; r < 16; ++r) {
                e0[r] = fexp2(st0[r] - m);
                e1[r] = fexp2(st1[r] - m);
            }
            float x0 = fmaxf(st0[0], st1[0]), x1 = fmaxf(st0[1], st1[1]);
            float x2 = fmaxf(st0[2], st1[2]), x3 = fmaxf(st0[3], st1[3]);
#pragma unroll
            for (int r = 4; r < 16; r += 4) {
                x0 = fmaxf(x0, fmaxf(st0[r], st1[r]));
                x1 = fmaxf(x1, fmaxf(st0[r + 1], st1[r + 1]));
                x2 = fmaxf(x2, fmaxf(st0[r + 2], st1[r + 2]));
                x3 = fmaxf(x3, fmaxf(st0[r + 3], st1[r + 3]));
            }
            float pmax = fmaxf(fmaxf(x0, x1), fmaxf(x2, x3));
            pmax = xmax32(pmax);
            if (!__all(pmax - m <= 8.0f)) { // defer-max threshold (log2 domain)
                const float mn = fmaxf(m, pmax);
                const float al = fexp2(m - mn); // power of 2: exact rescale
                l *= al; m = mn;
#pragma unroll
                for (int i = 0; i < 16; ++i) {
                    o0[i] *= al; o1[i] *= al;
                    e0[i] *= al; e1[i] *= al;
                }
            }
            float t0 = 0.f, t1 = 0.f, t2 = 0.f, t3 = 0.f;
#pragma unroll
            for (int r = 0; r < 16; r += 4) {
                t0 += e0[r] + e1[r];
                t1 += e0[r + 1] + e1[r + 1];
                t2 += e0[r + 2] + e1[r + 2];
                t3 += e0[r + 3] + e1[r + 3];
            }
            l += (t0 + t1) + (t2 + t3);
            st0 = e0; st1 = e1;
        }

        // ---- P -> PV B-frags in-register (cvt_pk + permlane32_swap, T12) ----
        f16x8 pb[4];
        {
            uint2v r0 = plswap(pk2h(st0[0], st0[1]), pk2h(st0[4], st0[5]));
            uint2v r1 = plswap(pk2h(st0[2], st0[3]), pk2h(st0[6], st0[7]));
            union { f16x8 v; unsigned u[4]; } w;
            w.u[0] = r0[0]; w.u[1] = r1[0]; w.u[2] = r0[1]; w.u[3] = r1[1];
            pb[0] = w.v;
            uint2v r2 = plswap(pk2h(st0[8], st0[9]), pk2h(st0[12], st0[13]));
            uint2v r3 = plswap(pk2h(st0[10], st0[11]), pk2h(st0[14], st0[15]));
            w.u[0] = r2[0]; w.u[1] = r3[0]; w.u[2] = r2[1]; w.u[3] = r3[1];
            pb[1] = w.v;
        }
        {
            uint2v r0 = plswap(pk2h(st1[0], st1[1]), pk2h(st1[4], st1[5]));
            uint2v r1 = plswap(pk2h(st1[2], st1[3]), pk2h(st1[6], st1[7]));
            union { f16x8 v; unsigned u[4]; } w;
            w.u[0] = r0[0]; w.u[1] = r1[0]; w.u[2] = r0[1]; w.u[3] = r1[1];
            pb[2] = w.v;
            uint2v r2 = plswap(pk2h(st1[8], st1[9]), pk2h(st1[12], st1[13]));
            uint2v r3 = plswap(pk2h(st1[10], st1[11]), pk2h(st1[14], st1[15]));
            w.u[0] = r2[0]; w.u[1] = r3[0]; w.u[2] = r2[1]; w.u[3] = r3[1];
            pb[3] = w.v;
        }

        // ---- PV: O^T[d][q] += V^T[d][s] * P^T[s][q] ----
        __builtin_amdgcn_s_setprio(1);
#pragma unroll
        for (int ks = 0; ks < 4; ++ks) {
            f16x8 v0 = *(const f16x8*)(Vs + ((ln * 128 + ks * 32 + hi * 16) ^ swA));
            f16x8 v1 = *(const f16x8*)(Vs + (((32 + ln) * 128 + ks * 32 + hi * 16) ^ swA));
            o0 = __builtin_amdgcn_mfma_f32_32x32x16_f16(v0, pb[ks], o0, 0, 0, 0);
            o1 = __builtin_amdgcn_mfma_f32_32x32x16_f16(v1, pb[ks], o1, 0, 0, 0);
        }
        __builtin_amdgcn_s_setprio(0);
    };

    // ---- 2-phase pipeline, tile 0 peeled (classic softmax path) ----
    STAGE(0, K0s, V0s);
    __syncthreads();
    STAGE(1, K1s, V1s);
    COMPUTE(K0s, V0s, true);
    __syncthreads();
    for (int it = 2; it < NT; it += 2) {
        STAGE(it, K0s, V0s);
        COMPUTE(K1s, V1s, false);
        __syncthreads();
        STAGE(it + 1, K1s, V1s);
        COMPUTE(K0s, V0s, false);
        __syncthreads();
    }
    COMPUTE(K1s, V1s, false); // tile NT-1

    // ---- epilogue: combine l across partner halves ONCE, normalize, store ----
    l = xsum32(l);
    const float invl = 1.f / l;
    float* optr = O + (((size_t)b * LL + qrow) * HH + h) * DD;
#pragma unroll
    for (int t = 0; t < 4; ++t) {
        f32x4 w;
        w[0] = o0[4 * t] * invl; w[1] = o0[4 * t + 1] * invl;
        w[2] = o0[4 * t + 2] * invl; w[3] = o0[4 * t + 3] * invl;
        *(f32x4*)(optr + t * 8 + hi * 4) = w;
    }
#pragma unroll
    for (int t = 0; t < 4; ++t) {
        f32x4 w;
        w[0] = o1[4 * t] * invl; w[1] = o1[4 * t + 1] * invl;
        w[2] = o1[4 * t + 2] * invl; w[3] = o1[4 * t + 3] * invl;
        *(f32x4*)(optr + 32 + t * 8 + hi * 4) = w;
    }
}

// ---------------- fallback (R1 kernel, used if ws too small) ----------------
typedef unsigned u2f __attribute__((ext_vector_type(2)));
__global__ __launch_bounds__(256) void fattn1(const float* __restrict__ Q,
                                              const float* __restrict__ K,
                                              const float* __restrict__ V,
                                              float* __restrict__ O) {
    __shared__ __align__(16) short Klds[KVB * 64];
    __shared__ __align__(16) short Vtlds[64 * KVB];
    __shared__ __align__(16) short Plds[4][16 * 64];

    const int tid = threadIdx.x;
    const int lane = tid & 63;
    const int wid = tid >> 6;
    const int g = (lane >> 4) & 3;
    const int c = lane & 15;

    const int bid = blockIdx.x;
    const int bh = bid >> 5;
    const int qt = bid & 31;
    const int b = bh >> 4;
    const int h = bh & 15;
    const int q0 = qt * 64;

    const int qrow = q0 + wid * 16 + c;
    const float* qptr = Q + (((size_t)b * LL + qrow) * HH + h) * EE;
    const float qs = 0.125f * 1.44269504088896340736f;
    f16x8 qf[2];
#pragma unroll
    for (int kk = 0; kk < 2; ++kk) {
        f32x4 a0 = *(const f32x4*)(qptr + kk * 32 + g * 8);
        f32x4 a1 = *(const f32x4*)(qptr + kk * 32 + g * 8 + 4);
        union { f16x8 v; unsigned u[4]; } cv;
        cv.u[0] = pk2h(a0[0] * qs, a0[1] * qs);
        cv.u[1] = pk2h(a0[2] * qs, a0[3] * qs);
        cv.u[2] = pk2h(a1[0] * qs, a1[1] * qs);
        cv.u[3] = pk2h(a1[2] * qs, a1[3] * qs);
        qf[kk] = cv.v;
    }

    f32x4 osacc[4];
    const f32x4 fzero = {0.f, 0.f, 0.f, 0.f};
#pragma unroll
    for (int i = 0; i < 4; ++i) osacc[i] = fzero;
    float m_run = -1e30f;
    float l_run = 0.f;

    const int km = tid & 15;
    const int kr = tid >> 4;

    for (int it = 0; it < NT; ++it) {
        const int s_glob = it * KVB;
        f32x4 kreg[4];
#pragma unroll
        for (int p = 0; p < 4; ++p) {
            int s = kr + p * 16;
            kreg[p] = *(const f32x4*)(K + (((size_t)b * SS + s_glob + s) * HH + h) * EE + km * 4);
        }
        f32x4 vreg[4];
#pragma unroll
        for (int p = 0; p < 4; ++p) {
            int s = kr * 4 + p;
            vreg[p] = *(const f32x4*)(V + (((size_t)b * SS + s_glob + s) * HH + h) * DD + km * 4);
        }
        __syncthreads();
#pragma unroll
        for (int p = 0; p < 4; ++p) {
            int s = kr + p * 16;
            u2f w;
            w.x = pk2h(kreg[p][0], kreg[p][1]);
            w.y = pk2h(kreg[p][2], kreg[p][3]);
            int byte = (s * 128 + km * 8) ^ ((s & 7) << 4);
            *(u2f*)((char*)Klds + byte) = w;
        }
#pragma unroll
        for (int i = 0; i < 4; ++i) {
            int d = km * 4 + i;
            u2f w;
            w.x = pk2h(vreg[0][i], vreg[1][i]);
            w.y = pk2h(vreg[2][i], vreg[3][i]);
            int byte = (d * 128 + kr * 8) ^ ((d & 7) << 4);
            *(u2f*)((char*)Vtlds + byte) = w;
        }
        __syncthreads();

        f32x4 stv[4];
#pragma unroll
        for (int fr = 0; fr < 4; ++fr) stv[fr] = fzero;
#pragma unroll
        for (int fr = 0; fr < 4; ++fr) {
            int s = fr * 16 + c;
            f16x8 kf0 = *(const f16x8*)((const char*)Klds + ((s * 128 + 16 * g) ^ ((s & 7) << 4)));
            stv[fr] = __builtin_amdgcn_mfma_f32_16x16x32_f16(kf0, qf[0], stv[fr], 0, 0, 0);
            f16x8 kf1 = *(const f16x8*)((const char*)Klds + ((s * 128 + 64 + 16 * g) ^ ((s & 7) << 4)));
            stv[fr] = __builtin_amdgcn_mfma_f32_16x16x32_f16(kf1, qf[1], stv[fr], 0, 0, 0);
        }

        float pmax = stv[0][0];
#pragma unroll
        for (int fr = 0; fr < 4; ++fr)
#pragma unroll
            for (int r = 0; r < 4; ++r) pmax = fmaxf(pmax, stv[fr][r]);
        pmax = fmaxf(pmax, __shfl_xor(pmax, 16));
        pmax = fmaxf(pmax, __shfl_xor(pmax, 32));
        float mnew = fmaxf(m_run, pmax);
        float alpha = fexp2(m_run - mnew);
        float tsum = 0.f;
#pragma unroll
        for (int fr = 0; fr < 4; ++fr)
#pragma unroll
            for (int r = 0; r < 4; ++r) {
                float e = fexp2(stv[fr][r] - mnew);
                stv[fr][r] = e;
                tsum += e;
            }
        tsum += __shfl_xor(tsum, 16);
        tsum += __shfl_xor(tsum, 32);
        l_run = l_run * alpha + tsum;
        m_run = mnew;
#pragma unroll
        for (int fr = 0; fr < 4; ++fr)
#pragma unroll
            for (int r = 0; r < 4; ++r) osacc[fr][r] *= alpha;

        short* plb = &Plds[wid][0];
#pragma unroll
        for (int fr = 0; fr < 4; ++fr) {
            u2f w;
            w.x = pk2h(stv[fr][0], stv[fr][1]);
            w.y = pk2h(stv[fr][2], stv[fr][3]);
            int byte = (c * 128 + fr * 32 + g * 8) ^ ((c & 7) << 4);
            *(u2f*)((char*)plb + byte) = w;
        }
        f16x8 pb0 = *(const f16x8*)((const char*)plb + ((c * 128 + 16 * g) ^ ((c & 7) << 4)));
        f16x8 pb1 = *(const f16x8*)((const char*)plb + ((c * 128 + 64 + 16 * g) ^ ((c & 7) << 4)));

#pragma unroll
        for (int fr = 0; fr < 4; ++fr) {
            int d = fr * 16 + c;
            f16x8 vf0 = *(const f16x8*)((const char*)Vtlds + ((d * 128 + 16 * g) ^ ((d & 7) << 4)));
            osacc[fr] = __builtin_amdgcn_mfma_f32_16x16x32_f16(vf0, pb0, osacc[fr], 0, 0, 0);
            f16x8 vf1 = *(const f16x8*)((const char*)Vtlds + ((d * 128 + 64 + 16 * g) ^ ((d & 7) << 4)));
            osacc[fr] = __builtin_amdgcn_mfma_f32_16x16x32_f16(vf1, pb1, osacc[fr], 0, 0, 0);
        }
    }

    float invl = 1.f / l_run;
    float* optr = O + (((size_t)b * LL + qrow) * HH + h) * DD;
#pragma unroll
    for (int fr = 0; fr < 4; ++fr) {
        f32x4 o;
        o[0] = osacc[fr][0] * invl;
        o[1] = osacc[fr][1] * invl;
        o[2] = osacc[fr][2] * invl;
        o[3] = osacc[fr][3] * invl;
        *(f32x4*)(optr + fr * 16 + g * 4) = o;
    }
}

extern "C" void kernel_launch(void* const* d_in, const int* in_sizes, int n_in,
                              void* d_out, int out_size, void* d_ws, size_t ws_size,
                              hipStream_t stream) {
    const float* Q = (const float*)d_in[0];
    const float* K = (const float*)d_in[1];
    const float* V = (const float*)d_in[2];
    float* Op = (float*)d_out;

    const size_t halfBytes = (size_t)NB * HH * SS * EE * 2; // 8 MB
    if (ws_size >= 2 * halfBytes) {
        unsigned short* Kht = (unsigned short*)d_ws;
        unsigned short* Vht = (unsigned short*)((char*)d_ws + halfBytes);
        hipLaunchKernelGGL(prepKV, dim3(2 * NB * HH * NT), dim3(256), 0, stream, K, V, Kht, Vht);
        hipLaunchKernelGGL(fattn3, dim3(NWG), dim3(256), 0, stream, Kht, Vht, Q, Op);
    } else {
        hipLaunchKernelGGL(fattn1, dim3(NB * HH * (LL / 64)), dim3(256), 0, stream, Q, K, V, Op);
    }
}

// Round 6
// 67.476 us; speedup vs baseline: 1.5651x; 1.0142x over previous
//
#include <hip/hip_runtime.h>
#include <hip/hip_bf16.h>
#include <string.h>

// FullAttention fwd: B=2, L=S=2048, H=16, E=D=64, fp32 in/out.
// R6: occupancy push. QBLK=64, 4 waves/block; wave pair (sh=0/1) splits each
// KV tile's s-range (32 s each) for the same 32 q-rows -> 1024 blocks =
// 4 blocks/CU = 4 waves/SIMD. Independent m/l/O partials per wave, LDS merge
// in epilogue. 32x32x16 f16 MFMA, swapped QK^T, in-register softmax (raw
// v_exp_f32) + P->B-frag via cvt_pkrtz + permlane32_swap. Pre-swizzled K/V^T
// f16 tile images in d_ws (prepKV), gll16 double-buffered staging.

#define NB 2
#define LL 2048
#define SS 2048
#define HH 16
#define EE 64
#define DD 64
#define KVB 64
#define NT (SS / KVB) /* 32 */
#define NWG2 (NB * HH * (LL / 64)) /* 1024 */

typedef _Float16 f16x8 __attribute__((ext_vector_type(8)));
typedef float f32x4 __attribute__((ext_vector_type(4)));
typedef float f32x16 __attribute__((ext_vector_type(16)));
typedef unsigned uint2v __attribute__((ext_vector_type(2)));
typedef unsigned uint4v __attribute__((ext_vector_type(4)));
typedef const __attribute__((address_space(1))) void* gas_p;
typedef __attribute__((address_space(3))) void* las_p;

__device__ __forceinline__ unsigned pk2h(float a, float b) {
    auto h = __builtin_amdgcn_cvt_pkrtz(a, b);
    unsigned u;
    __builtin_memcpy(&u, &h, 4);
    return u;
}

__device__ __forceinline__ float fexp2(float x) {
#if defined(__has_builtin) && __has_builtin(__builtin_amdgcn_exp2f)
    return __builtin_amdgcn_exp2f(x);
#else
    return exp2f(x);
#endif
}

__device__ __forceinline__ void gll16(const void* g, void* l) {
    __builtin_amdgcn_global_load_lds((gas_p)g, (las_p)l, 16, 0, 0);
}

__device__ __forceinline__ uint2v plswap(unsigned a, unsigned b) {
#if defined(__has_builtin) && __has_builtin(__builtin_amdgcn_permlane32_swap)
    return __builtin_amdgcn_permlane32_swap(a, b, false, false);
#else
    unsigned ax = (unsigned)__shfl_xor((int)a, 32);
    unsigned bx = (unsigned)__shfl_xor((int)b, 32);
    int l32 = (int)(threadIdx.x & 32);
    uint2v r;
    r[0] = l32 ? bx : a;
    r[1] = l32 ? b : ax;
    return r;
#endif
}

__device__ __forceinline__ float fbits(unsigned u) {
    float f; __builtin_memcpy(&f, &u, 4); return f;
}
__device__ __forceinline__ unsigned ubits(float f) {
    unsigned u; __builtin_memcpy(&u, &f, 4); return u;
}
__device__ __forceinline__ float xmax32(float x) {
    uint2v r = plswap(ubits(x), ubits(x));
    return fmaxf(fbits(r[0]), fbits(r[1]));
}
__device__ __forceinline__ float xsum32(float x) {
    uint2v r = plswap(ubits(x), ubits(x));
    return fbits(r[0]) + fbits(r[1]);
}

// ---------------- fused prep: K -> f16 tile image, V -> V^T f16 tile image --
// Kh tile (8KB): byte (s*128 + e*2) ^ ((s&7)<<4) holds f16 K[s0+s][e]
// Vth tile (8KB): byte (d*128 + s*2) ^ ((d&7)<<4) holds f16 V[s0+s][d]
__global__ __launch_bounds__(256) void prepKV(const float* __restrict__ K,
                                              const float* __restrict__ V,
                                              unsigned short* __restrict__ Kh,
                                              unsigned short* __restrict__ Vth) {
    const int NTILE = NB * HH * NT; // 1024
    const bool isV = blockIdx.x >= NTILE;
    const int tile = blockIdx.x & (NTILE - 1);
    const int it = tile & (NT - 1);
    const int bh = tile >> 5;
    const int b = bh >> 4, h = bh & 15;
    const int t = threadIdx.x;

    if (!isV) {
        const int s = t >> 2, ec = t & 3;
        const float* src = K + (((size_t)b * SS + it * KVB + s) * HH + h) * EE + ec * 16;
        f32x4 x0 = ((const f32x4*)src)[0];
        f32x4 x1 = ((const f32x4*)src)[1];
        f32x4 x2 = ((const f32x4*)src)[2];
        f32x4 x3 = ((const f32x4*)src)[3];
        uint4v c0, c1;
        c0.x = pk2h(x0[0], x0[1]); c0.y = pk2h(x0[2], x0[3]);
        c0.z = pk2h(x1[0], x1[1]); c0.w = pk2h(x1[2], x1[3]);
        c1.x = pk2h(x2[0], x2[1]); c1.y = pk2h(x2[2], x2[3]);
        c1.z = pk2h(x3[0], x3[1]); c1.w = pk2h(x3[2], x3[3]);
        char* dst = (char*)Kh + (size_t)tile * 8192;
        const int sw = (s & 7) << 4;
        *(uint4v*)(dst + ((s * 128 + ec * 32) ^ sw)) = c0;
        *(uint4v*)(dst + ((s * 128 + ec * 32 + 16) ^ sw)) = c1;
    } else {
        __shared__ float Vt[64 * 68];
        {
            const int s = t >> 2, dc = t & 3;
            const float* src = V + (((size_t)b * SS + it * KVB + s) * HH + h) * DD + dc * 16;
            f32x4 x0 = ((const f32x4*)src)[0];
            f32x4 x1 = ((const f32x4*)src)[1];
            f32x4 x2 = ((const f32x4*)src)[2];
            f32x4 x3 = ((const f32x4*)src)[3];
            float* row = Vt + s * 68 + dc * 16;
            ((f32x4*)row)[0] = x0; ((f32x4*)row)[1] = x1;
            ((f32x4*)row)[2] = x2; ((f32x4*)row)[3] = x3;
        }
        __syncthreads();
        {
            const int d = t >> 2, sc = t & 3;
            float w[16];
#pragma unroll
            for (int j = 0; j < 16; ++j) w[j] = Vt[(sc * 16 + j) * 68 + d];
            uint4v c0, c1;
            c0.x = pk2h(w[0], w[1]); c0.y = pk2h(w[2], w[3]);
            c0.z = pk2h(w[4], w[5]); c0.w = pk2h(w[6], w[7]);
            c1.x = pk2h(w[8], w[9]); c1.y = pk2h(w[10], w[11]);
            c1.z = pk2h(w[12], w[13]); c1.w = pk2h(w[14], w[15]);
            char* dst = (char*)Vth + (size_t)tile * 8192;
            const int sw = (d & 7) << 4;
            *(uint4v*)(dst + ((d * 128 + sc * 32) ^ sw)) = c0;
            *(uint4v*)(dst + ((d * 128 + sc * 32 + 16) ^ sw)) = c1;
        }
    }
}

// ---------------- main attention kernel (split-s, 4 waves/SIMD) ------------
__global__ __launch_bounds__(256, 4) void fattn4(const unsigned short* __restrict__ Kh,
                                                 const unsigned short* __restrict__ Vth,
                                                 const float* __restrict__ Q,
                                                 float* __restrict__ O) {
    __shared__ __align__(16) char LB[32768];
    __shared__ float msh[4][32];
    __shared__ float lsh[4][32];
    char* K0s = LB;
    char* K1s = LB + 8192;
    char* V0s = LB + 16384;
    char* V1s = LB + 24576;

    const int tid = threadIdx.x;
    const int lane = tid & 63;
    const int wid = tid >> 6;      // 0..3
    const int ln = lane & 31;      // q (and A-frag row index)
    const int hi = lane >> 5;      // k-half selector
    const int qg = wid >> 1;       // q-group (0: rows 0-31, 1: rows 32-63)
    const int sh = wid & 1;        // s-half of each KV tile (0: s 0-31, 1: s 32-63)

    const int bid0 = blockIdx.x;
    const int bid = (bid0 & 7) * (NWG2 >> 3) + (bid0 >> 3); // bijective XCD swizzle
    const int bh = bid >> 5;       // 0..31
    const int qt = bid & 31;
    const int b = bh >> 4, h = bh & 15;
    const int qrow = qt * 64 + qg * 32 + ln;

    // ---- Q B-frags: qf[ks] holds Q^T[k=e][n=q]: n=ln, e = ks*16 + hi*8 + j ----
    const float qs = 0.125f * 1.44269504088896340736f; // scale * log2(e)
    const float* qptr = Q + (((size_t)b * LL + qrow) * HH + h) * EE + hi * 8;
    f16x8 qf[4];
#pragma unroll
    for (int ks = 0; ks < 4; ++ks) {
        f32x4 a0 = *(const f32x4*)(qptr + ks * 16);
        f32x4 a1 = *(const f32x4*)(qptr + ks * 16 + 4);
        union { f16x8 v; unsigned u[4]; } cv;
        cv.u[0] = pk2h(a0[0] * qs, a0[1] * qs);
        cv.u[1] = pk2h(a0[2] * qs, a0[3] * qs);
        cv.u[2] = pk2h(a1[0] * qs, a1[1] * qs);
        cv.u[3] = pk2h(a1[2] * qs, a1[3] * qs);
        qf[ks] = cv.v;
    }

    f32x16 o0, o1; // O^T partial over this wave's s-halves: d 0-31 / 32-63, q=ln
#pragma unroll
    for (int i = 0; i < 16; ++i) { o0[i] = 0.f; o1[i] = 0.f; }
    float m = -1e30f, l = 0.f; // per-lane partials (own 16 s per tile)

    const char* Kg = (const char*)Kh + (size_t)bh * (NT * 8192);
    const char* Vg = (const char*)Vth + (size_t)bh * (NT * 8192);

    auto STAGE = [&](int it, char* Ks, char* Vs) {
        const size_t off = (size_t)it * 8192 + wid * 2048 + lane * 16;
        gll16(Kg + off, Ks + wid * 2048);
        gll16(Kg + off + 1024, Ks + wid * 2048 + 1024);
        gll16(Vg + off, Vs + wid * 2048);
        gll16(Vg + off + 1024, Vs + wid * 2048 + 1024);
    };

    const int swz = (ln & 7) << 4;
    const int srow = sh * 32 + ln;     // K-tile row this wave reads
    const int vcol = sh * 64;          // byte offset of this wave's s-window in V^T rows

    auto COMPUTE = [&](const char* Ks, const char* Vs) {
        // ---- QK^T: st = S^T[s-window][q] (one 32x32 frag, s = srow block) ----
        f32x16 st;
#pragma unroll
        for (int i = 0; i < 16; ++i) st[i] = 0.f;
        __builtin_amdgcn_s_setprio(1);
#pragma unroll
        for (int ks = 0; ks < 4; ++ks) {
            f16x8 kf = *(const f16x8*)(Ks + ((srow * 128 + ks * 32 + hi * 16) ^ swz));
            st = __builtin_amdgcn_mfma_f32_32x32x16_f16(kf, qf[ks], st, 0, 0, 0);
        }
        __builtin_amdgcn_s_setprio(0);

        // ---- online softmax over this wave's 32 s (log2 domain) ----
        float x0 = st[0], x1 = st[1], x2 = st[2], x3 = st[3];
#pragma unroll
        for (int r = 4; r < 16; r += 4) {
            x0 = fmaxf(x0, st[r]);
            x1 = fmaxf(x1, st[r + 1]);
            x2 = fmaxf(x2, st[r + 2]);
            x3 = fmaxf(x3, st[r + 3]);
        }
        float pmax = xmax32(fmaxf(fmaxf(x0, x1), fmaxf(x2, x3)));
        if (!__all(pmax - m <= 8.0f)) { // defer-max; first tile degenerates exactly
            const float mn = fmaxf(m, pmax);
            const float al = fexp2(m - mn); // pow2 (or 0 on first tile): exact
            l *= al; m = mn;
#pragma unroll
            for (int i = 0; i < 16; ++i) { o0[i] *= al; o1[i] *= al; }
        }
        float t0 = 0.f, t1 = 0.f, t2 = 0.f, t3 = 0.f;
#pragma unroll
        for (int r = 0; r < 16; r += 4) {
            st[r] = fexp2(st[r] - m);
            st[r + 1] = fexp2(st[r + 1] - m);
            st[r + 2] = fexp2(st[r + 2] - m);
            st[r + 3] = fexp2(st[r + 3] - m);
            t0 += st[r]; t1 += st[r + 1]; t2 += st[r + 2]; t3 += st[r + 3];
        }
        l += (t0 + t1) + (t2 + t3);

        // ---- P -> PV B-frag (T12) + PV, interleaved per 16-s slice ----
        {
            uint2v r0 = plswap(pk2h(st[0], st[1]), pk2h(st[4], st[5]));
            uint2v r1 = plswap(pk2h(st[2], st[3]), pk2h(st[6], st[7]));
            union { f16x8 v; unsigned u[4]; } w;
            w.u[0] = r0[0]; w.u[1] = r1[0]; w.u[2] = r0[1]; w.u[3] = r1[1];
            f16x8 v0 = *(const f16x8*)(Vs + ((ln * 128 + vcol + hi * 16) ^ swz));
            f16x8 v1 = *(const f16x8*)(Vs + (((32 + ln) * 128 + vcol + hi * 16) ^ swz));
            __builtin_amdgcn_s_setprio(1);
            o0 = __builtin_amdgcn_mfma_f32_32x32x16_f16(v0, w.v, o0, 0, 0, 0);
            o1 = __builtin_amdgcn_mfma_f32_32x32x16_f16(v1, w.v, o1, 0, 0, 0);
            __builtin_amdgcn_s_setprio(0);
        }
        {
            uint2v r2 = plswap(pk2h(st[8], st[9]), pk2h(st[12], st[13]));
            uint2v r3 = plswap(pk2h(st[10], st[11]), pk2h(st[14], st[15]));
            union { f16x8 v; unsigned u[4]; } w;
            w.u[0] = r2[0]; w.u[1] = r3[0]; w.u[2] = r2[1]; w.u[3] = r3[1];
            f16x8 v0 = *(const f16x8*)(Vs + ((ln * 128 + vcol + 32 + hi * 16) ^ swz));
            f16x8 v1 = *(const f16x8*)(Vs + (((32 + ln) * 128 + vcol + 32 + hi * 16) ^ swz));
            __builtin_amdgcn_s_setprio(1);
            o0 = __builtin_amdgcn_mfma_f32_32x32x16_f16(v0, w.v, o0, 0, 0, 0);
            o1 = __builtin_amdgcn_mfma_f32_32x32x16_f16(v1, w.v, o1, 0, 0, 0);
            __builtin_amdgcn_s_setprio(0);
        }
    };

    // ---- 2-phase double-buffered pipeline ----
    STAGE(0, K0s, V0s);
    __syncthreads();
    for (int it = 0; it < NT; it += 2) {
        if (it + 1 < NT) STAGE(it + 1, K1s, V1s);
        COMPUTE(K0s, V0s);
        __syncthreads();
        if (it + 2 < NT) STAGE(it + 2, K0s, V0s);
        COMPUTE(K1s, V1s);
        __syncthreads();
    }

    // ---- epilogue: merge wave pair (sh=0 / sh=1) via LDS ----
    l = xsum32(l); // combine hi-halves: wave-total l per q (uniform across pair)
    if (hi == 0) { msh[wid][ln] = m; lsh[wid][ln] = l; }
    __syncthreads();
    const float mo = msh[wid ^ 1][ln];
    const float lo = lsh[wid ^ 1][ln];
    const float ms = fmaxf(m, mo);
    const float f = fexp2(m - ms);
    const float fo = fexp2(mo - ms);
    const float lstar = l * f + lo * fo;

    float* pbuf = (float*)LB + qg * (32 * 65); // [32 q][65 d-padded] fp32
    if (sh == 1) {
#pragma unroll
        for (int r = 0; r < 16; ++r) {
            const int d = (r & 3) + 8 * (r >> 2) + 4 * hi;
            pbuf[ln * 65 + d] = o0[r] * f;
            pbuf[ln * 65 + 32 + d] = o1[r] * f;
        }
    }
    __syncthreads();
    if (sh == 0) {
        const float invl = 1.f / lstar;
        float* optr = O + (((size_t)b * LL + qrow) * HH + h) * DD;
#pragma unroll
        for (int t = 0; t < 4; ++t) {
            f32x4 w0, w1;
#pragma unroll
            for (int i = 0; i < 4; ++i) {
                const int d = t * 8 + hi * 4 + i;
                w0[i] = (o0[4 * t + i] * f + pbuf[ln * 65 + d]) * invl;
                w1[i] = (o1[4 * t + i] * f + pbuf[ln * 65 + 32 + d]) * invl;
            }
            *(f32x4*)(optr + t * 8 + hi * 4) = w0;
            *(f32x4*)(optr + 32 + t * 8 + hi * 4) = w1;
        }
    }
}

// ---------------- fallback (R1 kernel, used if ws too small) ----------------
typedef unsigned u2f __attribute__((ext_vector_type(2)));
__global__ __launch_bounds__(256) void fattn1(const float* __restrict__ Q,
                                              const float* __restrict__ K,
                                              const float* __restrict__ V,
                                              float* __restrict__ O) {
    __shared__ __align__(16) short Klds[KVB * 64];
    __shared__ __align__(16) short Vtlds[64 * KVB];
    __shared__ __align__(16) short Plds[4][16 * 64];

    const int tid = threadIdx.x;
    const int lane = tid & 63;
    const int wid = tid >> 6;
    const int g = (lane >> 4) & 3;
    const int c = lane & 15;

    const int bid = blockIdx.x;
    const int bh = bid >> 5;
    const int qt = bid & 31;
    const int b = bh >> 4;
    const int h = bh & 15;
    const int q0 = qt * 64;

    const int qrow = q0 + wid * 16 + c;
    const float* qptr = Q + (((size_t)b * LL + qrow) * HH + h) * EE;
    const float qs = 0.125f * 1.44269504088896340736f;
    f16x8 qf[2];
#pragma unroll
    for (int kk = 0; kk < 2; ++kk) {
        f32x4 a0 = *(const f32x4*)(qptr + kk * 32 + g * 8);
        f32x4 a1 = *(const f32x4*)(qptr + kk * 32 + g * 8 + 4);
        union { f16x8 v; unsigned u[4]; } cv;
        cv.u[0] = pk2h(a0[0] * qs, a0[1] * qs);
        cv.u[1] = pk2h(a0[2] * qs, a0[3] * qs);
        cv.u[2] = pk2h(a1[0] * qs, a1[1] * qs);
        cv.u[3] = pk2h(a1[2] * qs, a1[3] * qs);
        qf[kk] = cv.v;
    }

    f32x4 osacc[4];
    const f32x4 fzero = {0.f, 0.f, 0.f, 0.f};
#pragma unroll
    for (int i = 0; i < 4; ++i) osacc[i] = fzero;
    float m_run = -1e30f;
    float l_run = 0.f;

    const int km = tid & 15;
    const int kr = tid >> 4;

    for (int it = 0; it < NT; ++it) {
        const int s_glob = it * KVB;
        f32x4 kreg[4];
#pragma unroll
        for (int p = 0; p < 4; ++p) {
            int s = kr + p * 16;
            kreg[p] = *(const f32x4*)(K + (((size_t)b * SS + s_glob + s) * HH + h) * EE + km * 4);
        }
        f32x4 vreg[4];
#pragma unroll
        for (int p = 0; p < 4; ++p) {
            int s = kr * 4 + p;
            vreg[p] = *(const f32x4*)(V + (((size_t)b * SS + s_glob + s) * HH + h) * DD + km * 4);
        }
        __syncthreads();
#pragma unroll
        for (int p = 0; p < 4; ++p) {
            int s = kr + p * 16;
            u2f w;
            w.x = pk2h(kreg[p][0], kreg[p][1]);
            w.y = pk2h(kreg[p][2], kreg[p][3]);
            int byte = (s * 128 + km * 8) ^ ((s & 7) << 4);
            *(u2f*)((char*)Klds + byte) = w;
        }
#pragma unroll
        for (int i = 0; i < 4; ++i) {
            int d = km * 4 + i;
            u2f w;
            w.x = pk2h(vreg[0][i], vreg[1][i]);
            w.y = pk2h(vreg[2][i], vreg[3][i]);
            int byte = (d * 128 + kr * 8) ^ ((d & 7) << 4);
            *(u2f*)((char*)Vtlds + byte) = w;
        }
        __syncthreads();

        f32x4 stv[4];
#pragma unroll
        for (int fr = 0; fr < 4; ++fr) stv[fr] = fzero;
#pragma unroll
        for (int fr = 0; fr < 4; ++fr) {
            int s = fr * 16 + c;
            f16x8 kf0 = *(const f16x8*)((const char*)Klds + ((s * 128 + 16 * g) ^ ((s & 7) << 4)));
            stv[fr] = __builtin_amdgcn_mfma_f32_16x16x32_f16(kf0, qf[0], stv[fr], 0, 0, 0);
            f16x8 kf1 = *(const f16x8*)((const char*)Klds + ((s * 128 + 64 + 16 * g) ^ ((s & 7) << 4)));
            stv[fr] = __builtin_amdgcn_mfma_f32_16x16x32_f16(kf1, qf[1], stv[fr], 0, 0, 0);
        }

        float pmax = stv[0][0];
#pragma unroll
        for (int fr = 0; fr < 4; ++fr)
#pragma unroll
            for (int r = 0; r < 4; ++r) pmax = fmaxf(pmax, stv[fr][r]);
        pmax = fmaxf(pmax, __shfl_xor(pmax, 16));
        pmax = fmaxf(pmax, __shfl_xor(pmax, 32));
        float mnew = fmaxf(m_run, pmax);
        float alpha = fexp2(m_run - mnew);
        float tsum = 0.f;
#pragma unroll
        for (int fr = 0; fr < 4; ++fr)
#pragma unroll
            for (int r = 0; r < 4; ++r) {
                float e = fexp2(stv[fr][r] - mnew);
                stv[fr][r] = e;
                tsum += e;
            }
        tsum += __shfl_xor(tsum, 16);
        tsum += __shfl_xor(tsum, 32);
        l_run = l_run * alpha + tsum;
        m_run = mnew;
#pragma unroll
        for (int fr = 0; fr < 4; ++fr)
#pragma unroll
            for (int r = 0; r < 4; ++r) osacc[fr][r] *= alpha;

        short* plb = &Plds[wid][0];
#pragma unroll
        for (int fr = 0; fr < 4; ++fr) {
            u2f w;
            w.x = pk2h(stv[fr][0], stv[fr][1]);
            w.y = pk2h(stv[fr][2], stv[fr][3]);
            int byte = (c * 128 + fr * 32 + g * 8) ^ ((c & 7) << 4);
            *(u2f*)((char*)plb + byte) = w;
        }
        f16x8 pb0 = *(const f16x8*)((const char*)plb + ((c * 128 + 16 * g) ^ ((c & 7) << 4)));
        f16x8 pb1 = *(const f16x8*)((const char*)plb + ((c * 128 + 64 + 16 * g) ^ ((c & 7) << 4)));

#pragma unroll
        for (int fr = 0; fr < 4; ++fr) {
            int d = fr * 16 + c;
            f16x8 vf0 = *(const f16x8*)((const char*)Vtlds + ((d * 128 + 16 * g) ^ ((d & 7) << 4)));
            osacc[fr] = __builtin_amdgcn_mfma_f32_16x16x32_f16(vf0, pb0, osacc[fr], 0, 0, 0);
            f16x8 vf1 = *(const f16x8*)((const char*)Vtlds + ((d * 128 + 64 + 16 * g) ^ ((d & 7) << 4)));
            osacc[fr] = __builtin_amdgcn_mfma_f32_16x16x32_f16(vf1, pb1, osacc[fr], 0, 0, 0);
        }
    }

    float invl = 1.f / l_run;
    float* optr = O + (((size_t)b * LL + qrow) * HH + h) * DD;
#pragma unroll
    for (int fr = 0; fr < 4; ++fr) {
        f32x4 o;
        o[0] = osacc[fr][0] * invl;
        o[1] = osacc[fr][1] * invl;
        o[2] = osacc[fr][2] * invl;
        o[3] = osacc[fr][3] * invl;
        *(f32x4*)(optr + fr * 16 + g * 4) = o;
    }
}

extern "C" void kernel_launch(void* const* d_in, const int* in_sizes, int n_in,
                              void* d_out, int out_size, void* d_ws, size_t ws_size,
                              hipStream_t stream) {
    const float* Q = (const float*)d_in[0];
    const float* K = (const float*)d_in[1];
    const float* V = (const float*)d_in[2];
    float* Op = (float*)d_out;

    const size_t halfBytes = (size_t)NB * HH * SS * EE * 2; // 8 MB
    if (ws_size >= 2 * halfBytes) {
        unsigned short* Kht = (unsigned short*)d_ws;
        unsigned short* Vht = (unsigned short*)((char*)d_ws + halfBytes);
        hipLaunchKernelGGL(prepKV, dim3(2 * NB * HH * NT), dim3(256), 0, stream, K, V, Kht, Vht);
        hipLaunchKernelGGL(fattn4, dim3(NWG2), dim3(256), 0, stream, Kht, Vht, Q, Op);
    } else {
        hipLaunchKernelGGL(fattn1, dim3(NB * HH * (LL / 64)), dim3(256), 0, stream, Q, K, V, Op);
    }
}